// Round 1
// baseline (1140.205 us; speedup 1.0000x reference)
//
#include <hip/hip_runtime.h>

#define OBS 128
#define HID 64
#define ACT 32
#define TT  128
#define BB  4096

// tanh(v) = 1 - 2/(exp(2v)+1); exact at +-inf, ~1e-6 rel error (v_exp + v_rcp)
__device__ __forceinline__ float fast_tanh(float v) {
  const float e = __expf(2.0f * v);
  return 1.0f - 2.0f * __builtin_amdgcn_rcpf(e + 1.0f);
}

// broadcast value from lane l (compile-time-unrolled l) via v_readlane -> SGPR
__device__ __forceinline__ float bcast_lane(float v, int l) {
  return __int_as_float(__builtin_amdgcn_readlane(__float_as_int(v), l));
}

// ---------------------------------------------------------------------------
// Phase 1: capture  z1 = tanh(tanh(x @ Wc1 + bc1) @ Wc2 + bc2)  for all T*B
// rows; written directly to the `capt` region of d_out.
// Lane owns output column; Wc1/Wc2 columns live in VGPRs; x rows are
// wave-uniform -> scalar loads; mid broadcast via readlane.
// ---------------------------------------------------------------------------
__global__ __launch_bounds__(256, 2) void capture_kernel(
    const float* __restrict__ x,
    const float* __restrict__ Wc1, const float* __restrict__ bc1,
    const float* __restrict__ Wc2, const float* __restrict__ bc2,
    float* __restrict__ capt)
{
  const int tid  = threadIdx.x;
  const int lane = tid & 63;
  const int wuid = __builtin_amdgcn_readfirstlane(tid >> 6);

  float w1[OBS];
#pragma unroll
  for (int k = 0; k < OBS; ++k) w1[k] = Wc1[k * HID + lane];
  float w2[HID];
#pragma unroll
  for (int k = 0; k < HID; ++k) w2[k] = Wc2[k * HID + lane];
  const float b1 = bc1[lane];
  const float b2 = bc2[lane];

  const int stride = gridDim.x * 16;  // 4 waves/block * 4 rows/wave
  for (int r0 = (blockIdx.x * 4 + wuid) * 4; r0 < TT * BB; r0 += stride) {
    // ---- layer 1: per lane acc[r] = x[r] . Wc1[:,lane] ----
    float acc[4];
#pragma unroll
    for (int r = 0; r < 4; ++r) acc[r] = b1;
#pragma unroll
    for (int k = 0; k < OBS; k += 4) {
#pragma unroll
      for (int r = 0; r < 4; ++r) {
        const float4 xv = *(const float4*)(x + (size_t)(r0 + r) * OBS + k);
        acc[r] = fmaf(xv.x, w1[k],     acc[r]);
        acc[r] = fmaf(xv.y, w1[k + 1], acc[r]);
        acc[r] = fmaf(xv.z, w1[k + 2], acc[r]);
        acc[r] = fmaf(xv.w, w1[k + 3], acc[r]);
      }
    }
    float midv[4];
#pragma unroll
    for (int r = 0; r < 4; ++r) midv[r] = fast_tanh(acc[r]);

    // ---- layer 2: mid broadcast via readlane ----
    float a2[4];
#pragma unroll
    for (int r = 0; r < 4; ++r) a2[r] = b2;
#pragma unroll
    for (int k = 0; k < HID; ++k) {
#pragma unroll
      for (int r = 0; r < 4; ++r)
        a2[r] = fmaf(bcast_lane(midv[r], k), w2[k], a2[r]);
    }
#pragma unroll
    for (int r = 0; r < 4; ++r)
      capt[(size_t)(r0 + r) * HID + lane] = fast_tanh(a2[r]);
  }
}

// ---------------------------------------------------------------------------
// Phase 2: recurrence over T, independent per batch row.
// Each wave owns 4 batch rows for the whole scan. h kept per-lane (lane =
// hidden column); h/u broadcasts via readlane; a/g uniform scalar loads;
// z1 re-read from the capt region; outs/h_last written coalesced.
// Grid: 256 blocks * 4 waves * 4 rows = 4096 = B.
// ---------------------------------------------------------------------------
__global__ __launch_bounds__(256, 1) void recur_kernel(
    const float* __restrict__ h0,
    const float* __restrict__ g,
    const float* __restrict__ a,
    const float* __restrict__ Wp1, const float* __restrict__ bp1,
    const float* __restrict__ Wp2, const float* __restrict__ bp2,
    const float* __restrict__ z1buf,
    float* __restrict__ outs, float* __restrict__ hlast)
{
  const int tid  = threadIdx.x;
  const int lane = tid & 63;
  const int wuid = __builtin_amdgcn_readfirstlane(tid >> 6);

  float w1[HID + ACT];
#pragma unroll
  for (int k = 0; k < HID + ACT; ++k) w1[k] = Wp1[k * HID + lane];
  float w2[HID];
#pragma unroll
  for (int k = 0; k < HID; ++k) w2[k] = Wp2[k * HID + lane];
  const float b1 = bp1[lane];
  const float b2 = bp2[lane];

  const int row0 = (blockIdx.x * 4 + wuid) * 4;  // uniform (SGPR arithmetic)

  float hv[4];
#pragma unroll
  for (int r = 0; r < 4; ++r)
    hv[r] = h0[(size_t)(row0 + r) * HID + lane];

  for (int t = 0; t < TT; ++t) {
    const size_t tb = (size_t)t * BB + row0;

    // gating inputs (used only at the end of the step -> long latency slack)
    float z1v[4], gv[4];
#pragma unroll
    for (int r = 0; r < 4; ++r) z1v[r] = z1buf[(tb + r) * HID + lane];
#pragma unroll
    for (int r = 0; r < 4; ++r) gv[r] = g[tb + r];

    // ---- layer 1: za = [h ; a] ----
    float acc[4];
#pragma unroll
    for (int r = 0; r < 4; ++r) acc[r] = b1;

    // a-part first: uniform scalar loads issue early, latency hidden by h-part
#pragma unroll
    for (int k = 0; k < ACT; k += 4) {
#pragma unroll
      for (int r = 0; r < 4; ++r) {
        const float4 av = *(const float4*)(a + (tb + r) * ACT + k);
        acc[r] = fmaf(av.x, w1[HID + k],     acc[r]);
        acc[r] = fmaf(av.y, w1[HID + k + 1], acc[r]);
        acc[r] = fmaf(av.z, w1[HID + k + 2], acc[r]);
        acc[r] = fmaf(av.w, w1[HID + k + 3], acc[r]);
      }
    }
    // h-part via readlane broadcast
#pragma unroll
    for (int k = 0; k < HID; ++k) {
#pragma unroll
      for (int r = 0; r < 4; ++r)
        acc[r] = fmaf(bcast_lane(hv[r], k), w1[k], acc[r]);
    }

    float uv[4];
#pragma unroll
    for (int r = 0; r < 4; ++r) uv[r] = fast_tanh(acc[r]);

    // ---- layer 2 ----
    float acc2[4];
#pragma unroll
    for (int r = 0; r < 4; ++r) acc2[r] = b2;
#pragma unroll
    for (int k = 0; k < HID; ++k) {
#pragma unroll
      for (int r = 0; r < 4; ++r)
        acc2[r] = fmaf(bcast_lane(uv[r], k), w2[k], acc2[r]);
    }

    // ---- gated combine + outputs ----
#pragma unroll
    for (int r = 0; r < 4; ++r) {
      const float z2 = fast_tanh(acc2[r]);
      const float h_ = fmaf(gv[r], z2 - z1v[r], z1v[r]);  // (1-g)z1 + g z2
      hv[r] = h_;
      outs[(tb + r) * HID + lane] = h_;
    }
  }

#pragma unroll
  for (int r = 0; r < 4; ++r)
    hlast[(size_t)(row0 + r) * HID + lane] = hv[r];
}

extern "C" void kernel_launch(void* const* d_in, const int* in_sizes, int n_in,
                              void* d_out, int out_size, void* d_ws, size_t ws_size,
                              hipStream_t stream) {
  const float* x   = (const float*)d_in[0];
  const float* h0  = (const float*)d_in[1];
  const float* g   = (const float*)d_in[2];
  const float* a   = (const float*)d_in[3];
  const float* Wc1 = (const float*)d_in[4];
  const float* bc1 = (const float*)d_in[5];
  const float* Wc2 = (const float*)d_in[6];
  const float* bc2 = (const float*)d_in[7];
  const float* Wp1 = (const float*)d_in[8];
  const float* bp1 = (const float*)d_in[9];
  const float* Wp2 = (const float*)d_in[10];
  const float* bp2 = (const float*)d_in[11];

  float* out   = (float*)d_out;
  float* outs  = out;                                   // [T,B,H]
  float* hlast = out + (size_t)TT * BB * HID;           // [1,B,H]
  float* capt  = hlast + (size_t)BB * HID;              // [T,B,H]

  capture_kernel<<<dim3(4096), dim3(256), 0, stream>>>(x, Wc1, bc1, Wc2, bc2, capt);
  recur_kernel<<<dim3(BB / 16), dim3(256), 0, stream>>>(h0, g, a, Wp1, bp1, Wp2, bp2,
                                                        capt, outs, hlast);
}

// Round 2
// 807.692 us; speedup vs baseline: 1.4117x; 1.4117x over previous
//
#include <hip/hip_runtime.h>

#define OBS 128
#define HID 64
#define ACT 32
#define TT  128
#define BB  4096

// tanh(v) = 1 - 2/(exp(2v)+1); exact at +-inf, ~1e-6 rel error (v_exp + v_rcp)
__device__ __forceinline__ float fast_tanh(float v) {
  const float e = __expf(2.0f * v);
  return 1.0f - 2.0f * __builtin_amdgcn_rcpf(e + 1.0f);
}

// broadcast value from lane l (compile-time-unrolled l) via v_readlane -> SGPR
__device__ __forceinline__ float bcast_lane(float v, int l) {
  return __int_as_float(__builtin_amdgcn_readlane(__float_as_int(v), l));
}

// ---------------------------------------------------------------------------
// Phase 1: capture  z1 = tanh(tanh(x @ Wc1 + bc1) @ Wc2 + bc2)  for all T*B
// rows. Lane owns output column; Wc1/Wc2 columns pinned in VGPRs (asm fence
// prevents the compiler from sinking the loads into the loop — round-1 showed
// VGPR_Count=92, i.e. weights were being reloaded every iteration).
// 2 rows/wave-iter, 2 waves/SIMD target.
// ---------------------------------------------------------------------------
__global__ __launch_bounds__(256, 2) void capture_kernel(
    const float* __restrict__ x,
    const float* __restrict__ Wc1, const float* __restrict__ bc1,
    const float* __restrict__ Wc2, const float* __restrict__ bc2,
    float* __restrict__ capt)
{
  const int tid  = threadIdx.x;
  const int lane = tid & 63;
  const int wuid = __builtin_amdgcn_readfirstlane(tid >> 6);

  float w1[OBS];
#pragma unroll
  for (int k = 0; k < OBS; ++k) w1[k] = Wc1[k * HID + lane];
  float w2[HID];
#pragma unroll
  for (int k = 0; k < HID; ++k) w2[k] = Wc2[k * HID + lane];
  const float b1 = bc1[lane];
  const float b2 = bc2[lane];
  // pin: forces weights to stay resident in VGPRs across the row loop
#pragma unroll
  for (int k = 0; k < OBS; ++k) asm volatile("" : "+v"(w1[k]));
#pragma unroll
  for (int k = 0; k < HID; ++k) asm volatile("" : "+v"(w2[k]));

  const int stride = gridDim.x * 8;  // 4 waves/block * 2 rows/wave
  for (int r0 = (blockIdx.x * 4 + wuid) * 2; r0 < TT * BB; r0 += stride) {
    // ---- layer 1: split-k accumulation (2 chains per row) ----
    float accA[2], accB[2];
#pragma unroll
    for (int r = 0; r < 2; ++r) { accA[r] = b1; accB[r] = 0.0f; }
#pragma unroll
    for (int k = 0; k < OBS / 2; k += 4) {
#pragma unroll
      for (int r = 0; r < 2; ++r) {
        const float4 xa = *(const float4*)(x + (size_t)(r0 + r) * OBS + k);
        accA[r] = fmaf(xa.x, w1[k],     accA[r]);
        accA[r] = fmaf(xa.y, w1[k + 1], accA[r]);
        accA[r] = fmaf(xa.z, w1[k + 2], accA[r]);
        accA[r] = fmaf(xa.w, w1[k + 3], accA[r]);
        const int kb = k + OBS / 2;
        const float4 xb = *(const float4*)(x + (size_t)(r0 + r) * OBS + kb);
        accB[r] = fmaf(xb.x, w1[kb],     accB[r]);
        accB[r] = fmaf(xb.y, w1[kb + 1], accB[r]);
        accB[r] = fmaf(xb.z, w1[kb + 2], accB[r]);
        accB[r] = fmaf(xb.w, w1[kb + 3], accB[r]);
      }
    }
    float midv[2];
#pragma unroll
    for (int r = 0; r < 2; ++r) midv[r] = fast_tanh(accA[r] + accB[r]);

    // ---- layer 2: mid broadcast via readlane, 2 chains per row ----
    float a2A[2], a2B[2];
#pragma unroll
    for (int r = 0; r < 2; ++r) { a2A[r] = b2; a2B[r] = 0.0f; }
#pragma unroll
    for (int k = 0; k < HID / 2; ++k) {
#pragma unroll
      for (int r = 0; r < 2; ++r) {
        a2A[r] = fmaf(bcast_lane(midv[r], k), w2[k], a2A[r]);
        a2B[r] = fmaf(bcast_lane(midv[r], k + HID / 2), w2[k + HID / 2], a2B[r]);
      }
    }
#pragma unroll
    for (int r = 0; r < 2; ++r)
      capt[(size_t)(r0 + r) * HID + lane] = fast_tanh(a2A[r] + a2B[r]);
  }
}

// ---------------------------------------------------------------------------
// Phase 2: recurrence over T, independent per batch row.
// 2 rows/wave (was 4) -> 2048 waves -> 2 waves/SIMD. Weights pinned in VGPRs.
// Grid: 512 blocks * 4 waves * 2 rows = 4096 = B.
// ---------------------------------------------------------------------------
__global__ __launch_bounds__(256, 2) void recur_kernel(
    const float* __restrict__ h0,
    const float* __restrict__ g,
    const float* __restrict__ a,
    const float* __restrict__ Wp1, const float* __restrict__ bp1,
    const float* __restrict__ Wp2, const float* __restrict__ bp2,
    const float* __restrict__ z1buf,
    float* __restrict__ outs, float* __restrict__ hlast)
{
  const int tid  = threadIdx.x;
  const int lane = tid & 63;
  const int wuid = __builtin_amdgcn_readfirstlane(tid >> 6);

  float w1[HID + ACT];
#pragma unroll
  for (int k = 0; k < HID + ACT; ++k) w1[k] = Wp1[k * HID + lane];
  float w2[HID];
#pragma unroll
  for (int k = 0; k < HID; ++k) w2[k] = Wp2[k * HID + lane];
  const float b1 = bp1[lane];
  const float b2 = bp2[lane];
  // pin weights in VGPRs (see capture_kernel comment)
#pragma unroll
  for (int k = 0; k < HID + ACT; ++k) asm volatile("" : "+v"(w1[k]));
#pragma unroll
  for (int k = 0; k < HID; ++k) asm volatile("" : "+v"(w2[k]));

  const int row0 = (blockIdx.x * 4 + wuid) * 2;  // uniform (SGPR arithmetic)

  float hv[2];
#pragma unroll
  for (int r = 0; r < 2; ++r)
    hv[r] = h0[(size_t)(row0 + r) * HID + lane];

  for (int t = 0; t < TT; ++t) {
    const size_t tb = (size_t)t * BB + row0;

    // gating inputs issued early; used only at the end of the step
    float z1v[2], gv[2];
#pragma unroll
    for (int r = 0; r < 2; ++r) z1v[r] = z1buf[(tb + r) * HID + lane];
#pragma unroll
    for (int r = 0; r < 2; ++r) gv[r] = g[tb + r];

    // ---- layer 1: za = [h ; a], split-k chains ----
    float accA[2], accB[2];
#pragma unroll
    for (int r = 0; r < 2; ++r) { accA[r] = b1; accB[r] = 0.0f; }

    // a-part (uniform broadcast float4 loads)
#pragma unroll
    for (int k = 0; k < ACT; k += 8) {
#pragma unroll
      for (int r = 0; r < 2; ++r) {
        const float4 aa = *(const float4*)(a + (tb + r) * ACT + k);
        accA[r] = fmaf(aa.x, w1[HID + k],     accA[r]);
        accA[r] = fmaf(aa.y, w1[HID + k + 1], accA[r]);
        accA[r] = fmaf(aa.z, w1[HID + k + 2], accA[r]);
        accA[r] = fmaf(aa.w, w1[HID + k + 3], accA[r]);
        const float4 ab = *(const float4*)(a + (tb + r) * ACT + k + 4);
        accB[r] = fmaf(ab.x, w1[HID + k + 4], accB[r]);
        accB[r] = fmaf(ab.y, w1[HID + k + 5], accB[r]);
        accB[r] = fmaf(ab.z, w1[HID + k + 6], accB[r]);
        accB[r] = fmaf(ab.w, w1[HID + k + 7], accB[r]);
      }
    }
    // h-part via readlane broadcast, 2 chains
#pragma unroll
    for (int k = 0; k < HID / 2; ++k) {
#pragma unroll
      for (int r = 0; r < 2; ++r) {
        accA[r] = fmaf(bcast_lane(hv[r], k), w1[k], accA[r]);
        accB[r] = fmaf(bcast_lane(hv[r], k + HID / 2), w1[k + HID / 2], accB[r]);
      }
    }

    float uv[2];
#pragma unroll
    for (int r = 0; r < 2; ++r) uv[r] = fast_tanh(accA[r] + accB[r]);

    // ---- layer 2, 2 chains ----
    float c2A[2], c2B[2];
#pragma unroll
    for (int r = 0; r < 2; ++r) { c2A[r] = b2; c2B[r] = 0.0f; }
#pragma unroll
    for (int k = 0; k < HID / 2; ++k) {
#pragma unroll
      for (int r = 0; r < 2; ++r) {
        c2A[r] = fmaf(bcast_lane(uv[r], k), w2[k], c2A[r]);
        c2B[r] = fmaf(bcast_lane(uv[r], k + HID / 2), w2[k + HID / 2], c2B[r]);
      }
    }

    // ---- gated combine + outputs ----
#pragma unroll
    for (int r = 0; r < 2; ++r) {
      const float z2 = fast_tanh(c2A[r] + c2B[r]);
      const float h_ = fmaf(gv[r], z2 - z1v[r], z1v[r]);  // (1-g)z1 + g z2
      hv[r] = h_;
      outs[(tb + r) * HID + lane] = h_;
    }
  }

#pragma unroll
  for (int r = 0; r < 2; ++r)
    hlast[(size_t)(row0 + r) * HID + lane] = hv[r];
}

extern "C" void kernel_launch(void* const* d_in, const int* in_sizes, int n_in,
                              void* d_out, int out_size, void* d_ws, size_t ws_size,
                              hipStream_t stream) {
  const float* x   = (const float*)d_in[0];
  const float* h0  = (const float*)d_in[1];
  const float* g   = (const float*)d_in[2];
  const float* a   = (const float*)d_in[3];
  const float* Wc1 = (const float*)d_in[4];
  const float* bc1 = (const float*)d_in[5];
  const float* Wc2 = (const float*)d_in[6];
  const float* bc2 = (const float*)d_in[7];
  const float* Wp1 = (const float*)d_in[8];
  const float* bp1 = (const float*)d_in[9];
  const float* Wp2 = (const float*)d_in[10];
  const float* bp2 = (const float*)d_in[11];

  float* out   = (float*)d_out;
  float* outs  = out;                                   // [T,B,H]
  float* hlast = out + (size_t)TT * BB * HID;           // [1,B,H]
  float* capt  = hlast + (size_t)BB * HID;              // [T,B,H]

  capture_kernel<<<dim3(2048), dim3(256), 0, stream>>>(x, Wc1, bc1, Wc2, bc2, capt);
  recur_kernel<<<dim3(BB / 8), dim3(256), 0, stream>>>(h0, g, a, Wp1, bp1, Wp2, bp2,
                                                       capt, outs, hlast);
}

// Round 3
// 410.439 us; speedup vs baseline: 2.7780x; 1.9679x over previous
//
#include <hip/hip_runtime.h>

#define OBS 128
#define HID 64
#define ACT 32
#define TT  128
#define BB  4096

typedef __attribute__((ext_vector_type(8))) short bf16x8;  // 8 bf16 (4 VGPRs)
typedef __attribute__((ext_vector_type(4))) float f32x4;

// tanh(v) = 1 - 2/(exp(2v)+1); exact at +-inf, ~1e-6 rel error (v_exp + v_rcp)
__device__ __forceinline__ float fast_tanh(float v) {
  const float e = __expf(2.0f * v);
  return 1.0f - 2.0f * __builtin_amdgcn_rcpf(e + 1.0f);
}

// f32 -> bf16 bits, round-to-nearest-even (inputs finite; no NaN path needed)
__device__ __forceinline__ short f2bf(float f) {
  const unsigned u = __float_as_uint(f);
  return (short)((u + 0x7FFFu + ((u >> 16) & 1u)) >> 16);
}

// broadcast value from lane l (compile-time-unrolled l) via v_readlane -> SGPR
__device__ __forceinline__ float bcast_lane(float v, int l) {
  return __int_as_float(__builtin_amdgcn_readlane(__float_as_int(v), l));
}

// ---------------------------------------------------------------------------
// Phase 1: capture  z1 = tanh(tanh(x @ Wc1 + bc1) @ Wc2 + bc2), MFMA bf16.
//
// Transposed-operand formulation: C1^T = Wc1^T (A) x^T (B), 16x16x32 MFMA.
//   A-frag: lane holds row M=c1 (= lane&15 within tile), 8 k-elems (group G=lane>>4)
//   B-frag: lane holds col N=data-row r (= lane&15), same k-map as A
//   C/D   : lane holds (M-idx = 4G+reg, N-idx = r)   [m89-verified layout]
// So after layer 1, lane (r,G) holds mid^T[c1 = 16m+4G+reg][r] for m,reg in 0..3.
// Layer 2 (C2^T = Wc2^T mid^T) consumes these DIRECTLY as B-fragments by
// choosing Wc2^T's k-map to match: frag kk, elem j:
//   j<4 : k = 32kk      + 4G + j      (= lane's m'=2kk,   reg=j)
//   j>=4: k = 32kk + 16 + 4G + (j-4)  (= lane's m'=2kk+1, reg=j-4)
// A and B agree on the k-bijection => result exact. Zero LDS / shuffles.
// Biases ride in as the MFMA C-input. Stores coalesce as float4.
// ---------------------------------------------------------------------------
__global__ __launch_bounds__(256, 2) void capture_mfma(
    const float* __restrict__ x,
    const float* __restrict__ Wc1, const float* __restrict__ bc1,
    const float* __restrict__ Wc2, const float* __restrict__ bc2,
    float* __restrict__ capt)
{
  const int tid  = threadIdx.x;
  const int lane = tid & 63;
  const int r    = lane & 15;   // tile-row (N dim) / weight output column
  const int G    = lane >> 4;   // k-group
  const int wave = blockIdx.x * (blockDim.x >> 6) + (tid >> 6);
  const int nwaves = gridDim.x * (blockDim.x >> 6);

  // ---- weight fragments (loaded once, reused over all tiles) ----
  bf16x8 w1t[4][4];  // [m = c1-tile][kk], standard k-map: k = 32kk + 8G + j
#pragma unroll
  for (int m = 0; m < 4; ++m)
#pragma unroll
    for (int kk = 0; kk < 4; ++kk) {
      bf16x8 f;
#pragma unroll
      for (int j = 0; j < 8; ++j)
        f[j] = f2bf(Wc1[(kk * 32 + 8 * G + j) * HID + 16 * m + r]);
      w1t[m][kk] = f;
    }
  bf16x8 w2t[4][2];  // [m2][kk], custom k-map matching lane-resident mid^T
#pragma unroll
  for (int m = 0; m < 4; ++m)
#pragma unroll
    for (int kk = 0; kk < 2; ++kk) {
      bf16x8 f;
#pragma unroll
      for (int j = 0; j < 8; ++j) {
        const int k = (j < 4) ? (32 * kk + 4 * G + j)
                              : (32 * kk + 16 + 4 * G + (j - 4));
        f[j] = f2bf(Wc2[k * HID + 16 * m + r]);
      }
      w2t[m][kk] = f;
    }
  f32x4 bias1[4], bias2[4];
#pragma unroll
  for (int m = 0; m < 4; ++m) {
    bias1[m] = *(const f32x4*)(bc1 + 16 * m + 4 * G);
    bias2[m] = *(const f32x4*)(bc2 + 16 * m + 4 * G);
  }

  for (int tile = wave; tile < (TT * BB) / 16; tile += nwaves) {
    // ---- x fragments: lane loads 8 consecutive k per kk-step ----
    const float* xrow = x + ((size_t)tile * 16 + r) * OBS;
    bf16x8 xa[4];
#pragma unroll
    for (int kk = 0; kk < 4; ++kk) {
      const float4 lo = *(const float4*)(xrow + kk * 32 + 8 * G);
      const float4 hi = *(const float4*)(xrow + kk * 32 + 8 * G + 4);
      bf16x8 f;
      f[0] = f2bf(lo.x); f[1] = f2bf(lo.y); f[2] = f2bf(lo.z); f[3] = f2bf(lo.w);
      f[4] = f2bf(hi.x); f[5] = f2bf(hi.y); f[6] = f2bf(hi.z); f[7] = f2bf(hi.w);
      xa[kk] = f;
    }

    // ---- layer 1: 16 MFMA, bias as C-in ----
    float um[4][4];
#pragma unroll
    for (int m = 0; m < 4; ++m) {
      f32x4 acc = bias1[m];
#pragma unroll
      for (int kk = 0; kk < 4; ++kk)
        acc = __builtin_amdgcn_mfma_f32_16x16x32_bf16(w1t[m][kk], xa[kk], acc, 0, 0, 0);
#pragma unroll
      for (int q = 0; q < 4; ++q) um[m][q] = fast_tanh(acc[q]);
    }

    // ---- assemble layer-2 B fragments from lane-resident mid^T ----
    bf16x8 b2[2];
#pragma unroll
    for (int kk = 0; kk < 2; ++kk) {
      bf16x8 f;
#pragma unroll
      for (int j = 0; j < 4; ++j) f[j]     = f2bf(um[2 * kk][j]);
#pragma unroll
      for (int j = 0; j < 4; ++j) f[4 + j] = f2bf(um[2 * kk + 1][j]);
      b2[kk] = f;
    }

    // ---- layer 2: 8 MFMA + tanh + coalesced float4 stores ----
    float* crow = capt + ((size_t)tile * 16 + r) * HID;
#pragma unroll
    for (int m = 0; m < 4; ++m) {
      f32x4 acc = bias2[m];
#pragma unroll
      for (int kk = 0; kk < 2; ++kk)
        acc = __builtin_amdgcn_mfma_f32_16x16x32_bf16(w2t[m][kk], b2[kk], acc, 0, 0, 0);
      float4 o;
      o.x = fast_tanh(acc[0]); o.y = fast_tanh(acc[1]);
      o.z = fast_tanh(acc[2]); o.w = fast_tanh(acc[3]);
      *(float4*)(crow + 16 * m + 4 * G) = o;
    }
  }
}

// ---------------------------------------------------------------------------
// Phase 2: recurrence over T — UNCHANGED from round 2 (one variable at a time;
// MFMA port of this kernel is next once bf16 precision is validated).
// ---------------------------------------------------------------------------
__global__ __launch_bounds__(256, 2) void recur_kernel(
    const float* __restrict__ h0,
    const float* __restrict__ g,
    const float* __restrict__ a,
    const float* __restrict__ Wp1, const float* __restrict__ bp1,
    const float* __restrict__ Wp2, const float* __restrict__ bp2,
    const float* __restrict__ z1buf,
    float* __restrict__ outs, float* __restrict__ hlast)
{
  const int tid  = threadIdx.x;
  const int lane = tid & 63;
  const int wuid = __builtin_amdgcn_readfirstlane(tid >> 6);

  float w1[HID + ACT];
#pragma unroll
  for (int k = 0; k < HID + ACT; ++k) w1[k] = Wp1[k * HID + lane];
  float w2[HID];
#pragma unroll
  for (int k = 0; k < HID; ++k) w2[k] = Wp2[k * HID + lane];
  const float b1 = bp1[lane];
  const float b2 = bp2[lane];
#pragma unroll
  for (int k = 0; k < HID + ACT; ++k) asm volatile("" : "+v"(w1[k]));
#pragma unroll
  for (int k = 0; k < HID; ++k) asm volatile("" : "+v"(w2[k]));

  const int row0 = (blockIdx.x * 4 + wuid) * 2;

  float hv[2];
#pragma unroll
  for (int r = 0; r < 2; ++r)
    hv[r] = h0[(size_t)(row0 + r) * HID + lane];

  for (int t = 0; t < TT; ++t) {
    const size_t tb = (size_t)t * BB + row0;

    float z1v[2], gv[2];
#pragma unroll
    for (int r = 0; r < 2; ++r) z1v[r] = z1buf[(tb + r) * HID + lane];
#pragma unroll
    for (int r = 0; r < 2; ++r) gv[r] = g[tb + r];

    float accA[2], accB[2];
#pragma unroll
    for (int r = 0; r < 2; ++r) { accA[r] = b1; accB[r] = 0.0f; }

#pragma unroll
    for (int k = 0; k < ACT; k += 8) {
#pragma unroll
      for (int r = 0; r < 2; ++r) {
        const float4 aa = *(const float4*)(a + (tb + r) * ACT + k);
        accA[r] = fmaf(aa.x, w1[HID + k],     accA[r]);
        accA[r] = fmaf(aa.y, w1[HID + k + 1], accA[r]);
        accA[r] = fmaf(aa.z, w1[HID + k + 2], accA[r]);
        accA[r] = fmaf(aa.w, w1[HID + k + 3], accA[r]);
        const float4 ab = *(const float4*)(a + (tb + r) * ACT + k + 4);
        accB[r] = fmaf(ab.x, w1[HID + k + 4], accB[r]);
        accB[r] = fmaf(ab.y, w1[HID + k + 5], accB[r]);
        accB[r] = fmaf(ab.z, w1[HID + k + 6], accB[r]);
        accB[r] = fmaf(ab.w, w1[HID + k + 7], accB[r]);
      }
    }
#pragma unroll
    for (int k = 0; k < HID / 2; ++k) {
#pragma unroll
      for (int r = 0; r < 2; ++r) {
        accA[r] = fmaf(bcast_lane(hv[r], k), w1[k], accA[r]);
        accB[r] = fmaf(bcast_lane(hv[r], k + HID / 2), w1[k + HID / 2], accB[r]);
      }
    }

    float uv[2];
#pragma unroll
    for (int r = 0; r < 2; ++r) uv[r] = fast_tanh(accA[r] + accB[r]);

    float c2A[2], c2B[2];
#pragma unroll
    for (int r = 0; r < 2; ++r) { c2A[r] = b2; c2B[r] = 0.0f; }
#pragma unroll
    for (int k = 0; k < HID / 2; ++k) {
#pragma unroll
      for (int r = 0; r < 2; ++r) {
        c2A[r] = fmaf(bcast_lane(uv[r], k), w2[k], c2A[r]);
        c2B[r] = fmaf(bcast_lane(uv[r], k + HID / 2), w2[k + HID / 2], c2B[r]);
      }
    }

#pragma unroll
    for (int r = 0; r < 2; ++r) {
      const float z2 = fast_tanh(c2A[r] + c2B[r]);
      const float h_ = fmaf(gv[r], z2 - z1v[r], z1v[r]);
      hv[r] = h_;
      outs[(tb + r) * HID + lane] = h_;
    }
  }

#pragma unroll
  for (int r = 0; r < 2; ++r)
    hlast[(size_t)(row0 + r) * HID + lane] = hv[r];
}

extern "C" void kernel_launch(void* const* d_in, const int* in_sizes, int n_in,
                              void* d_out, int out_size, void* d_ws, size_t ws_size,
                              hipStream_t stream) {
  const float* x   = (const float*)d_in[0];
  const float* h0  = (const float*)d_in[1];
  const float* g   = (const float*)d_in[2];
  const float* a   = (const float*)d_in[3];
  const float* Wc1 = (const float*)d_in[4];
  const float* bc1 = (const float*)d_in[5];
  const float* Wc2 = (const float*)d_in[6];
  const float* bc2 = (const float*)d_in[7];
  const float* Wp1 = (const float*)d_in[8];
  const float* bp1 = (const float*)d_in[9];
  const float* Wp2 = (const float*)d_in[10];
  const float* bp2 = (const float*)d_in[11];

  float* out   = (float*)d_out;
  float* outs  = out;                                   // [T,B,H]
  float* hlast = out + (size_t)TT * BB * HID;           // [1,B,H]
  float* capt  = hlast + (size_t)BB * HID;              // [T,B,H]

  capture_mfma<<<dim3(1024), dim3(256), 0, stream>>>(x, Wc1, bc1, Wc2, bc2, capt);
  recur_kernel<<<dim3(BB / 8), dim3(256), 0, stream>>>(h0, g, a, Wp1, bp1, Wp2, bp2,
                                                       capt, outs, hlast);
}

// Round 4
// 242.318 us; speedup vs baseline: 4.7054x; 1.6938x over previous
//
#include <hip/hip_runtime.h>

#define OBS 128
#define HID 64
#define ACT 32
#define TT  128
#define BB  4096

typedef __attribute__((ext_vector_type(8))) short bf16x8;  // 8 bf16 (4 VGPRs)
typedef __attribute__((ext_vector_type(4))) float f32x4;

// tanh(v) = 1 - 2/(exp(2v)+1); exact at +-inf, ~1e-6 rel error (v_exp + v_rcp)
__device__ __forceinline__ float fast_tanh(float v) {
  const float e = __expf(2.0f * v);
  return 1.0f - 2.0f * __builtin_amdgcn_rcpf(e + 1.0f);
}

// f32 -> bf16 bits, round-to-nearest-even (inputs finite; no NaN path needed)
__device__ __forceinline__ short f2bf(float f) {
  const unsigned u = __float_as_uint(f);
  return (short)((u + 0x7FFFu + ((u >> 16) & 1u)) >> 16);
}

// pack two f32x4 (C/D-layout register quads) into one bf16x8 B-fragment
__device__ __forceinline__ bf16x8 pack2(const f32x4 s0, const f32x4 s1) {
  bf16x8 f;
  f[0] = f2bf(s0[0]); f[1] = f2bf(s0[1]); f[2] = f2bf(s0[2]); f[3] = f2bf(s0[3]);
  f[4] = f2bf(s1[0]); f[5] = f2bf(s1[1]); f[6] = f2bf(s1[2]); f[7] = f2bf(s1[3]);
  return f;
}

// ---------------------------------------------------------------------------
// Phase 1: capture  z1 = tanh(tanh(x @ Wc1 + bc1) @ Wc2 + bc2), MFMA bf16.
// (unchanged from round 3 — ~80 us, near its ~64 us memory floor)
// Transposed-operand formulation: C1^T = Wc1^T (A) x^T (B), 16x16x32 MFMA.
// Layer-2 consumes layer-1's lane-resident output directly as B-fragments via
// a custom-but-consistent A/B k-bijection. Zero LDS / shuffles / barriers.
// ---------------------------------------------------------------------------
__global__ __launch_bounds__(256, 2) void capture_mfma(
    const float* __restrict__ x,
    const float* __restrict__ Wc1, const float* __restrict__ bc1,
    const float* __restrict__ Wc2, const float* __restrict__ bc2,
    float* __restrict__ capt)
{
  const int tid  = threadIdx.x;
  const int lane = tid & 63;
  const int r    = lane & 15;   // tile-row (N dim) / weight output column
  const int G    = lane >> 4;   // k-group
  const int wave = blockIdx.x * (blockDim.x >> 6) + (tid >> 6);
  const int nwaves = gridDim.x * (blockDim.x >> 6);

  bf16x8 w1t[4][4];  // standard k-map: k = 32kk + 8G + j
#pragma unroll
  for (int m = 0; m < 4; ++m)
#pragma unroll
    for (int kk = 0; kk < 4; ++kk) {
      bf16x8 f;
#pragma unroll
      for (int j = 0; j < 8; ++j)
        f[j] = f2bf(Wc1[(kk * 32 + 8 * G + j) * HID + 16 * m + r]);
      w1t[m][kk] = f;
    }
  bf16x8 w2t[4][2];  // custom k-map matching lane-resident mid^T
#pragma unroll
  for (int m = 0; m < 4; ++m)
#pragma unroll
    for (int kk = 0; kk < 2; ++kk) {
      bf16x8 f;
#pragma unroll
      for (int j = 0; j < 8; ++j) {
        const int k = (j < 4) ? (32 * kk + 4 * G + j)
                              : (32 * kk + 16 + 4 * G + (j - 4));
        f[j] = f2bf(Wc2[k * HID + 16 * m + r]);
      }
      w2t[m][kk] = f;
    }
  f32x4 bias1[4], bias2[4];
#pragma unroll
  for (int m = 0; m < 4; ++m) {
    bias1[m] = *(const f32x4*)(bc1 + 16 * m + 4 * G);
    bias2[m] = *(const f32x4*)(bc2 + 16 * m + 4 * G);
  }

  for (int tile = wave; tile < (TT * BB) / 16; tile += nwaves) {
    const float* xrow = x + ((size_t)tile * 16 + r) * OBS;
    bf16x8 xa[4];
#pragma unroll
    for (int kk = 0; kk < 4; ++kk) {
      const float4 lo = *(const float4*)(xrow + kk * 32 + 8 * G);
      const float4 hi = *(const float4*)(xrow + kk * 32 + 8 * G + 4);
      bf16x8 f;
      f[0] = f2bf(lo.x); f[1] = f2bf(lo.y); f[2] = f2bf(lo.z); f[3] = f2bf(lo.w);
      f[4] = f2bf(hi.x); f[5] = f2bf(hi.y); f[6] = f2bf(hi.z); f[7] = f2bf(hi.w);
      xa[kk] = f;
    }

    float um[4][4];
#pragma unroll
    for (int m = 0; m < 4; ++m) {
      f32x4 acc = bias1[m];
#pragma unroll
      for (int kk = 0; kk < 4; ++kk)
        acc = __builtin_amdgcn_mfma_f32_16x16x32_bf16(w1t[m][kk], xa[kk], acc, 0, 0, 0);
#pragma unroll
      for (int q = 0; q < 4; ++q) um[m][q] = fast_tanh(acc[q]);
    }

    bf16x8 b2[2];
#pragma unroll
    for (int kk = 0; kk < 2; ++kk) {
      bf16x8 f;
#pragma unroll
      for (int j = 0; j < 4; ++j) f[j]     = f2bf(um[2 * kk][j]);
#pragma unroll
      for (int j = 0; j < 4; ++j) f[4 + j] = f2bf(um[2 * kk + 1][j]);
      b2[kk] = f;
    }

    float* crow = capt + ((size_t)tile * 16 + r) * HID;
#pragma unroll
    for (int m = 0; m < 4; ++m) {
      f32x4 acc = bias2[m];
#pragma unroll
      for (int kk = 0; kk < 2; ++kk)
        acc = __builtin_amdgcn_mfma_f32_16x16x32_bf16(w2t[m][kk], b2[kk], acc, 0, 0, 0);
      float4 o;
      o.x = fast_tanh(acc[0]); o.y = fast_tanh(acc[1]);
      o.z = fast_tanh(acc[2]); o.w = fast_tanh(acc[3]);
      *(float4*)(crow + 16 * m + 4 * G) = o;
    }
  }
}

// ---------------------------------------------------------------------------
// Phase 2: recurrence, MFMA bf16, transposed-operand form.
// One wave owns 16 batch rows for the whole T-scan (lane r = lane&15 owns
// batch row tile*16+r). h lives in registers in the MFMA C/D layout
// h^T[16m+4G+reg][r]; layer-2's output layout == next step's layer-1
// B-fragment layout (same custom k-bijection as capture's layer 2), so the
// recurrence never touches LDS. Gate is lane-local (g[row] is the lane's own
// scalar). (z1, a, g) are register-double-buffered one step ahead so the
// vmcnt-counted waits keep HBM loads in flight under the h dependency chain.
// Grid: 256 blocks x 64 threads = 1 wave/CU (B/16 tiles).
// ---------------------------------------------------------------------------
#define R_LOADS(t, Z, AL, AH, GV)                                   \
  do {                                                              \
    const size_t rb = (size_t)(t) * BB + row;                       \
    const float* zp = z1buf + rb * HID;                             \
    Z##0 = *(const f32x4*)(zp + 4 * G);                             \
    Z##1 = *(const f32x4*)(zp + 16 + 4 * G);                        \
    Z##2 = *(const f32x4*)(zp + 32 + 4 * G);                        \
    Z##3 = *(const f32x4*)(zp + 48 + 4 * G);                        \
    const float* ap = a + rb * ACT + 8 * G;                         \
    AL = *(const float4*)(ap);                                      \
    AH = *(const float4*)(ap + 4);                                  \
    GV = g[rb];                                                     \
  } while (0)

#define R_COMPUTE(t, Z0, Z1, Z2, Z3, AL, AH, GV)                               \
  do {                                                                         \
    bf16x8 ab;                                                                 \
    ab[0] = f2bf(AL.x); ab[1] = f2bf(AL.y); ab[2] = f2bf(AL.z);                \
    ab[3] = f2bf(AL.w); ab[4] = f2bf(AH.x); ab[5] = f2bf(AH.y);                \
    ab[6] = f2bf(AH.z); ab[7] = f2bf(AH.w);                                    \
    f32x4 um[4];                                                               \
    _Pragma("unroll")                                                          \
    for (int m = 0; m < 4; ++m) {                                              \
      f32x4 acc = bias1[m];                                                    \
      acc = __builtin_amdgcn_mfma_f32_16x16x32_bf16(w1h[m][0], hb0, acc, 0, 0, 0); \
      acc = __builtin_amdgcn_mfma_f32_16x16x32_bf16(w1h[m][1], hb1, acc, 0, 0, 0); \
      acc = __builtin_amdgcn_mfma_f32_16x16x32_bf16(w1a[m], ab, acc, 0, 0, 0); \
      f32x4 u;                                                                 \
      u[0] = fast_tanh(acc[0]); u[1] = fast_tanh(acc[1]);                      \
      u[2] = fast_tanh(acc[2]); u[3] = fast_tanh(acc[3]);                      \
      um[m] = u;                                                               \
    }                                                                          \
    const bf16x8 ub0 = pack2(um[0], um[1]);                                    \
    const bf16x8 ub1 = pack2(um[2], um[3]);                                    \
    const size_t ob = ((size_t)(t) * BB + row) * HID;                          \
    _Pragma("unroll")                                                          \
    for (int m = 0; m < 4; ++m) {                                              \
      f32x4 acc = bias2[m];                                                    \
      acc = __builtin_amdgcn_mfma_f32_16x16x32_bf16(w2t[m][0], ub0, acc, 0, 0, 0); \
      acc = __builtin_amdgcn_mfma_f32_16x16x32_bf16(w2t[m][1], ub1, acc, 0, 0, 0); \
      const f32x4 zz = (m == 0) ? Z0 : (m == 1) ? Z1 : (m == 2) ? Z2 : Z3;     \
      f32x4 hn;                                                                \
      hn[0] = fmaf(GV, fast_tanh(acc[0]) - zz[0], zz[0]);                      \
      hn[1] = fmaf(GV, fast_tanh(acc[1]) - zz[1], zz[1]);                      \
      hn[2] = fmaf(GV, fast_tanh(acc[2]) - zz[2], zz[2]);                      \
      hn[3] = fmaf(GV, fast_tanh(acc[3]) - zz[3], zz[3]);                      \
      hm[m] = hn;                                                              \
      *(f32x4*)(outs + ob + 16 * m + 4 * G) = hn;                              \
    }                                                                          \
    hb0 = pack2(hm[0], hm[1]);                                                 \
    hb1 = pack2(hm[2], hm[3]);                                                 \
  } while (0)

__global__ __launch_bounds__(64, 1) void recur_mfma(
    const float* __restrict__ h0,
    const float* __restrict__ g,
    const float* __restrict__ a,
    const float* __restrict__ Wp1, const float* __restrict__ bp1,
    const float* __restrict__ Wp2, const float* __restrict__ bp2,
    const float* __restrict__ z1buf,
    float* __restrict__ outs, float* __restrict__ hlast)
{
  const int lane = threadIdx.x & 63;
  const int r    = lane & 15;
  const int G    = lane >> 4;
  const int row  = blockIdx.x * 16 + r;   // batch row owned by this lane

  // ---- weight fragments (resident for the whole scan) ----
  bf16x8 w1h[4][2], w2t[4][2], w1a[4];
#pragma unroll
  for (int m = 0; m < 4; ++m) {
#pragma unroll
    for (int kk = 0; kk < 2; ++kk) {
      bf16x8 f1, f2;
#pragma unroll
      for (int j = 0; j < 8; ++j) {
        const int k = (j < 4) ? (32 * kk + 4 * G + j)
                              : (32 * kk + 16 + 4 * G + (j - 4));
        f1[j] = f2bf(Wp1[k * HID + 16 * m + r]);
        f2[j] = f2bf(Wp2[k * HID + 16 * m + r]);
      }
      w1h[m][kk] = f1;
      w2t[m][kk] = f2;
    }
    bf16x8 fa;  // a-part, standard map: k = HID + 8G + j
#pragma unroll
    for (int j = 0; j < 8; ++j)
      fa[j] = f2bf(Wp1[(HID + 8 * G + j) * HID + 16 * m + r]);
    w1a[m] = fa;
  }
  f32x4 bias1[4], bias2[4];
#pragma unroll
  for (int m = 0; m < 4; ++m) {
    bias1[m] = *(const f32x4*)(bp1 + 16 * m + 4 * G);
    bias2[m] = *(const f32x4*)(bp2 + 16 * m + 4 * G);
  }

  // ---- h state in C/D layout ----
  f32x4 hm[4];
#pragma unroll
  for (int m = 0; m < 4; ++m)
    hm[m] = *(const f32x4*)(h0 + (size_t)row * HID + 16 * m + 4 * G);
  bf16x8 hb0 = pack2(hm[0], hm[1]);
  bf16x8 hb1 = pack2(hm[2], hm[3]);

  // ---- double-buffered step inputs ----
  f32x4 zA0, zA1, zA2, zA3, zB0, zB1, zB2, zB3;
  float4 aAl, aAh, aBl, aBh;
  float gA, gB;

  R_LOADS(0, zA, aAl, aAh, gA);

  for (int t = 0; t < TT; t += 2) {
    const int t2 = (t + 2 < TT) ? (t + 2) : (TT - 1);  // clamp (redundant reload)
    R_LOADS(t + 1, zB, aBl, aBh, gB);
    R_COMPUTE(t, zA0, zA1, zA2, zA3, aAl, aAh, gA);
    R_LOADS(t2, zA, aAl, aAh, gA);
    R_COMPUTE(t + 1, zB0, zB1, zB2, zB3, aBl, aBh, gB);
  }

#pragma unroll
  for (int m = 0; m < 4; ++m)
    *(f32x4*)(hlast + (size_t)row * HID + 16 * m + 4 * G) = hm[m];
}

extern "C" void kernel_launch(void* const* d_in, const int* in_sizes, int n_in,
                              void* d_out, int out_size, void* d_ws, size_t ws_size,
                              hipStream_t stream) {
  const float* x   = (const float*)d_in[0];
  const float* h0  = (const float*)d_in[1];
  const float* g   = (const float*)d_in[2];
  const float* a   = (const float*)d_in[3];
  const float* Wc1 = (const float*)d_in[4];
  const float* bc1 = (const float*)d_in[5];
  const float* Wc2 = (const float*)d_in[6];
  const float* bc2 = (const float*)d_in[7];
  const float* Wp1 = (const float*)d_in[8];
  const float* bp1 = (const float*)d_in[9];
  const float* Wp2 = (const float*)d_in[10];
  const float* bp2 = (const float*)d_in[11];

  float* out   = (float*)d_out;
  float* outs  = out;                                   // [T,B,H]
  float* hlast = out + (size_t)TT * BB * HID;           // [1,B,H]
  float* capt  = hlast + (size_t)BB * HID;              // [T,B,H]

  capture_mfma<<<dim3(1024), dim3(256), 0, stream>>>(x, Wc1, bc1, Wc2, bc2, capt);
  recur_mfma<<<dim3(BB / 16), dim3(64), 0, stream>>>(h0, g, a, Wp1, bp1, Wp2, bp2,
                                                     capt, outs, hlast);
}

// Round 5
// 230.253 us; speedup vs baseline: 4.9520x; 1.0524x over previous
//
#include <hip/hip_runtime.h>

#define OBS 128
#define HID 64
#define ACT 32
#define TT  128
#define BB  4096

typedef __attribute__((ext_vector_type(8))) short bf16x8;  // 8 bf16 (4 VGPRs)
typedef __attribute__((ext_vector_type(4))) float f32x4;

// tanh(v) = 1 - 2/(exp(2v)+1); exact at +-inf, ~1e-6 rel error (v_exp + v_rcp)
__device__ __forceinline__ float fast_tanh(float v) {
  const float e = __expf(2.0f * v);
  return 1.0f - 2.0f * __builtin_amdgcn_rcpf(e + 1.0f);
}

// f32 -> bf16 bits, round-to-nearest-even (inputs finite; no NaN path needed)
__device__ __forceinline__ short f2bf(float f) {
  const unsigned u = __float_as_uint(f);
  return (short)((u + 0x7FFFu + ((u >> 16) & 1u)) >> 16);
}

// pack two f32x4 (C/D-layout register quads) into one bf16x8 B-fragment
__device__ __forceinline__ bf16x8 pack2(const f32x4 s0, const f32x4 s1) {
  bf16x8 f;
  f[0] = f2bf(s0[0]); f[1] = f2bf(s0[1]); f[2] = f2bf(s0[2]); f[3] = f2bf(s0[3]);
  f[4] = f2bf(s1[0]); f[5] = f2bf(s1[1]); f[6] = f2bf(s1[2]); f[7] = f2bf(s1[3]);
  return f;
}

// ---------------------------------------------------------------------------
// Prep: pre-convert capture weights into fragment-ordered bf16 in d_ws.
// Layout: frag f in [0,16): w1t[m=f>>2][kk=f&3]; f in [16,24): w2t[(f-16)>>1][(f-16)&1].
// Each (frag,lane) slot is a contiguous 16 B bf16x8 => capture_mfma reloads
// its whole weight set with 24 perfectly-coalesced dwordx4 loads (24 KB,
// L2-resident). This removes the round-4 pathology where regalloc chose to
// re-materialize 192 scattered 4 B weight loads per tile (VGPR_Count=84,
// all pipes idle, 165 us).
// ---------------------------------------------------------------------------
__global__ void prep_capture_weights(const float* __restrict__ Wc1,
                                     const float* __restrict__ Wc2,
                                     short* __restrict__ ws)
{
  const int idx = blockIdx.x * blockDim.x + threadIdx.x;  // 0..1535
  if (idx >= 24 * 64) return;
  const int f = idx >> 6, lane = idx & 63;
  const int r = lane & 15, G = lane >> 4;
  short o[8];
  if (f < 16) {
    const int m = f >> 2, kk = f & 3;  // standard k-map: k = 32kk + 8G + j
#pragma unroll
    for (int j = 0; j < 8; ++j)
      o[j] = f2bf(Wc1[(kk * 32 + 8 * G + j) * HID + 16 * m + r]);
  } else {
    const int m = (f - 16) >> 1, kk = (f - 16) & 1;  // custom k-map (matches mid^T)
#pragma unroll
    for (int j = 0; j < 8; ++j) {
      const int k = (j < 4) ? (32 * kk + 4 * G + j)
                            : (32 * kk + 16 + 4 * G + (j - 4));
      o[j] = f2bf(Wc2[k * HID + 16 * m + r]);
    }
  }
  bf16x8 v;
#pragma unroll
  for (int j = 0; j < 8; ++j) v[j] = o[j];
  *(bf16x8*)(ws + (size_t)idx * 8) = v;
}

// ---------------------------------------------------------------------------
// Phase 1: capture  z1 = tanh(tanh(x @ Wc1 + bc1) @ Wc2 + bc2), MFMA bf16.
// Transposed-operand formulation (validated rounds 3-4): C1^T = Wc1^T x^T,
// layer-2 consumes layer-1's lane-resident output directly as B-fragments.
// Weights come from the prep kernel's fragment-ordered ws buffer (coalesced
// dwordx4) and are pinned in VGPRs; budget 256 via launch_bounds(256,2),
// persistent state ~170 regs -> no spill (round-2 lesson).
// ---------------------------------------------------------------------------
__global__ __launch_bounds__(256, 2) void capture_mfma(
    const float* __restrict__ x,
    const short* __restrict__ wsw,
    const float* __restrict__ bc1, const float* __restrict__ bc2,
    float* __restrict__ capt)
{
  const int tid  = threadIdx.x;
  const int lane = tid & 63;
  const int r    = lane & 15;   // tile-row (N dim)
  const int G    = lane >> 4;   // k-group
  const int wave = blockIdx.x * (blockDim.x >> 6) + (tid >> 6);
  const int nwaves = gridDim.x * (blockDim.x >> 6);

  const bf16x8* wf = (const bf16x8*)wsw;
  bf16x8 w1t[4][4];
#pragma unroll
  for (int m = 0; m < 4; ++m)
#pragma unroll
    for (int kk = 0; kk < 4; ++kk)
      w1t[m][kk] = wf[(m * 4 + kk) * 64 + lane];
  bf16x8 w2t[4][2];
#pragma unroll
  for (int m = 0; m < 4; ++m)
#pragma unroll
    for (int kk = 0; kk < 2; ++kk)
      w2t[m][kk] = wf[(16 + m * 2 + kk) * 64 + lane];
  f32x4 bias1[4], bias2[4];
#pragma unroll
  for (int m = 0; m < 4; ++m) {
    bias1[m] = *(const f32x4*)(bc1 + 16 * m + 4 * G);
    bias2[m] = *(const f32x4*)(bc2 + 16 * m + 4 * G);
  }
  // pin fragments in VGPRs so they stay resident across the tile loop
#pragma unroll
  for (int m = 0; m < 4; ++m) {
#pragma unroll
    for (int kk = 0; kk < 4; ++kk) asm volatile("" : "+v"(w1t[m][kk]));
#pragma unroll
    for (int kk = 0; kk < 2; ++kk) asm volatile("" : "+v"(w2t[m][kk]));
    asm volatile("" : "+v"(bias1[m]), "+v"(bias2[m]));
  }

  for (int tile = wave; tile < (TT * BB) / 16; tile += nwaves) {
    const float* xrow = x + ((size_t)tile * 16 + r) * OBS;
    bf16x8 xa[4];
#pragma unroll
    for (int kk = 0; kk < 4; ++kk) {
      const float4 lo = *(const float4*)(xrow + kk * 32 + 8 * G);
      const float4 hi = *(const float4*)(xrow + kk * 32 + 8 * G + 4);
      bf16x8 f;
      f[0] = f2bf(lo.x); f[1] = f2bf(lo.y); f[2] = f2bf(lo.z); f[3] = f2bf(lo.w);
      f[4] = f2bf(hi.x); f[5] = f2bf(hi.y); f[6] = f2bf(hi.z); f[7] = f2bf(hi.w);
      xa[kk] = f;
    }

    float um[4][4];
#pragma unroll
    for (int m = 0; m < 4; ++m) {
      f32x4 acc = bias1[m];
#pragma unroll
      for (int kk = 0; kk < 4; ++kk)
        acc = __builtin_amdgcn_mfma_f32_16x16x32_bf16(w1t[m][kk], xa[kk], acc, 0, 0, 0);
#pragma unroll
      for (int q = 0; q < 4; ++q) um[m][q] = fast_tanh(acc[q]);
    }

    bf16x8 b2[2];
#pragma unroll
    for (int kk = 0; kk < 2; ++kk) {
      bf16x8 f;
#pragma unroll
      for (int j = 0; j < 4; ++j) f[j]     = f2bf(um[2 * kk][j]);
#pragma unroll
      for (int j = 0; j < 4; ++j) f[4 + j] = f2bf(um[2 * kk + 1][j]);
      b2[kk] = f;
    }

    float* crow = capt + ((size_t)tile * 16 + r) * HID;
#pragma unroll
    for (int m = 0; m < 4; ++m) {
      f32x4 acc = bias2[m];
#pragma unroll
      for (int kk = 0; kk < 2; ++kk)
        acc = __builtin_amdgcn_mfma_f32_16x16x32_bf16(w2t[m][kk], b2[kk], acc, 0, 0, 0);
      float4 o;
      o.x = fast_tanh(acc[0]); o.y = fast_tanh(acc[1]);
      o.z = fast_tanh(acc[2]); o.w = fast_tanh(acc[3]);
      *(float4*)(crow + 16 * m + 4 * G) = o;
    }
  }
}

// ---------------------------------------------------------------------------
// Phase 2: recurrence, MFMA bf16, transposed-operand form — UNCHANGED from
// round 4 (~77 us, near its ~53 us memory floor). One wave owns 16 batch rows
// for the whole T-scan; h stays in registers in the MFMA C/D layout; layer-2
// output layout == next step's layer-1 B-fragment layout; zero LDS.
// ---------------------------------------------------------------------------
#define R_LOADS(t, Z, AL, AH, GV)                                   \
  do {                                                              \
    const size_t rb = (size_t)(t) * BB + row;                       \
    const float* zp = z1buf + rb * HID;                             \
    Z##0 = *(const f32x4*)(zp + 4 * G);                             \
    Z##1 = *(const f32x4*)(zp + 16 + 4 * G);                        \
    Z##2 = *(const f32x4*)(zp + 32 + 4 * G);                        \
    Z##3 = *(const f32x4*)(zp + 48 + 4 * G);                        \
    const float* ap = a + rb * ACT + 8 * G;                         \
    AL = *(const float4*)(ap);                                      \
    AH = *(const float4*)(ap + 4);                                  \
    GV = g[rb];                                                     \
  } while (0)

#define R_COMPUTE(t, Z0, Z1, Z2, Z3, AL, AH, GV)                               \
  do {                                                                         \
    bf16x8 ab;                                                                 \
    ab[0] = f2bf(AL.x); ab[1] = f2bf(AL.y); ab[2] = f2bf(AL.z);                \
    ab[3] = f2bf(AL.w); ab[4] = f2bf(AH.x); ab[5] = f2bf(AH.y);                \
    ab[6] = f2bf(AH.z); ab[7] = f2bf(AH.w);                                    \
    f32x4 um[4];                                                               \
    _Pragma("unroll")                                                          \
    for (int m = 0; m < 4; ++m) {                                              \
      f32x4 acc = bias1[m];                                                    \
      acc = __builtin_amdgcn_mfma_f32_16x16x32_bf16(w1h[m][0], hb0, acc, 0, 0, 0); \
      acc = __builtin_amdgcn_mfma_f32_16x16x32_bf16(w1h[m][1], hb1, acc, 0, 0, 0); \
      acc = __builtin_amdgcn_mfma_f32_16x16x32_bf16(w1a[m], ab, acc, 0, 0, 0); \
      f32x4 u;                                                                 \
      u[0] = fast_tanh(acc[0]); u[1] = fast_tanh(acc[1]);                      \
      u[2] = fast_tanh(acc[2]); u[3] = fast_tanh(acc[3]);                      \
      um[m] = u;                                                               \
    }                                                                          \
    const bf16x8 ub0 = pack2(um[0], um[1]);                                    \
    const bf16x8 ub1 = pack2(um[2], um[3]);                                    \
    const size_t ob = ((size_t)(t) * BB + row) * HID;                          \
    _Pragma("unroll")                                                          \
    for (int m = 0; m < 4; ++m) {                                              \
      f32x4 acc = bias2[m];                                                    \
      acc = __builtin_amdgcn_mfma_f32_16x16x32_bf16(w2t[m][0], ub0, acc, 0, 0, 0); \
      acc = __builtin_amdgcn_mfma_f32_16x16x32_bf16(w2t[m][1], ub1, acc, 0, 0, 0); \
      const f32x4 zz = (m == 0) ? Z0 : (m == 1) ? Z1 : (m == 2) ? Z2 : Z3;     \
      f32x4 hn;                                                                \
      hn[0] = fmaf(GV, fast_tanh(acc[0]) - zz[0], zz[0]);                      \
      hn[1] = fmaf(GV, fast_tanh(acc[1]) - zz[1], zz[1]);                      \
      hn[2] = fmaf(GV, fast_tanh(acc[2]) - zz[2], zz[2]);                      \
      hn[3] = fmaf(GV, fast_tanh(acc[3]) - zz[3], zz[3]);                      \
      hm[m] = hn;                                                              \
      *(f32x4*)(outs + ob + 16 * m + 4 * G) = hn;                              \
    }                                                                          \
    hb0 = pack2(hm[0], hm[1]);                                                 \
    hb1 = pack2(hm[2], hm[3]);                                                 \
  } while (0)

__global__ __launch_bounds__(64, 1) void recur_mfma(
    const float* __restrict__ h0,
    const float* __restrict__ g,
    const float* __restrict__ a,
    const float* __restrict__ Wp1, const float* __restrict__ bp1,
    const float* __restrict__ Wp2, const float* __restrict__ bp2,
    const float* __restrict__ z1buf,
    float* __restrict__ outs, float* __restrict__ hlast)
{
  const int lane = threadIdx.x & 63;
  const int r    = lane & 15;
  const int G    = lane >> 4;
  const int row  = blockIdx.x * 16 + r;   // batch row owned by this lane

  bf16x8 w1h[4][2], w2t[4][2], w1a[4];
#pragma unroll
  for (int m = 0; m < 4; ++m) {
#pragma unroll
    for (int kk = 0; kk < 2; ++kk) {
      bf16x8 f1, f2;
#pragma unroll
      for (int j = 0; j < 8; ++j) {
        const int k = (j < 4) ? (32 * kk + 4 * G + j)
                              : (32 * kk + 16 + 4 * G + (j - 4));
        f1[j] = f2bf(Wp1[k * HID + 16 * m + r]);
        f2[j] = f2bf(Wp2[k * HID + 16 * m + r]);
      }
      w1h[m][kk] = f1;
      w2t[m][kk] = f2;
    }
    bf16x8 fa;  // a-part, standard map: k = HID + 8G + j
#pragma unroll
    for (int j = 0; j < 8; ++j)
      fa[j] = f2bf(Wp1[(HID + 8 * G + j) * HID + 16 * m + r]);
    w1a[m] = fa;
  }
  f32x4 bias1[4], bias2[4];
#pragma unroll
  for (int m = 0; m < 4; ++m) {
    bias1[m] = *(const f32x4*)(bp1 + 16 * m + 4 * G);
    bias2[m] = *(const f32x4*)(bp2 + 16 * m + 4 * G);
  }

  f32x4 hm[4];
#pragma unroll
  for (int m = 0; m < 4; ++m)
    hm[m] = *(const f32x4*)(h0 + (size_t)row * HID + 16 * m + 4 * G);
  bf16x8 hb0 = pack2(hm[0], hm[1]);
  bf16x8 hb1 = pack2(hm[2], hm[3]);

  f32x4 zA0, zA1, zA2, zA3, zB0, zB1, zB2, zB3;
  float4 aAl, aAh, aBl, aBh;
  float gA, gB;

  R_LOADS(0, zA, aAl, aAh, gA);

  for (int t = 0; t < TT; t += 2) {
    const int t2 = (t + 2 < TT) ? (t + 2) : (TT - 1);  // clamp (redundant reload)
    R_LOADS(t + 1, zB, aBl, aBh, gB);
    R_COMPUTE(t, zA0, zA1, zA2, zA3, aAl, aAh, gA);
    R_LOADS(t2, zA, aAl, aAh, gA);
    R_COMPUTE(t + 1, zB0, zB1, zB2, zB3, aBl, aBh, gB);
  }

#pragma unroll
  for (int m = 0; m < 4; ++m)
    *(f32x4*)(hlast + (size_t)row * HID + 16 * m + 4 * G) = hm[m];
}

extern "C" void kernel_launch(void* const* d_in, const int* in_sizes, int n_in,
                              void* d_out, int out_size, void* d_ws, size_t ws_size,
                              hipStream_t stream) {
  const float* x   = (const float*)d_in[0];
  const float* h0  = (const float*)d_in[1];
  const float* g   = (const float*)d_in[2];
  const float* a   = (const float*)d_in[3];
  const float* Wc1 = (const float*)d_in[4];
  const float* bc1 = (const float*)d_in[5];
  const float* Wc2 = (const float*)d_in[6];
  const float* bc2 = (const float*)d_in[7];
  const float* Wp1 = (const float*)d_in[8];
  const float* bp1 = (const float*)d_in[9];
  const float* Wp2 = (const float*)d_in[10];
  const float* bp2 = (const float*)d_in[11];

  float* out   = (float*)d_out;
  float* outs  = out;                                   // [T,B,H]
  float* hlast = out + (size_t)TT * BB * HID;           // [1,B,H]
  float* capt  = hlast + (size_t)BB * HID;              // [T,B,H]
  short* wsw   = (short*)d_ws;                          // 24 KB fragment buffer

  prep_capture_weights<<<dim3(6), dim3(256), 0, stream>>>(Wc1, Wc2, wsw);
  capture_mfma<<<dim3(2048), dim3(256), 0, stream>>>(x, wsw, bc1, bc2, capt);
  recur_mfma<<<dim3(BB / 16), dim3(64), 0, stream>>>(h0, g, a, Wp1, bp1, Wp2, bp2,
                                                     capt, outs, hlast);
}

// Round 6
// 228.086 us; speedup vs baseline: 4.9990x; 1.0095x over previous
//
#include <hip/hip_runtime.h>

#define OBS 128
#define HID 64
#define ACT 32
#define TT  128
#define BB  4096

typedef __attribute__((ext_vector_type(8))) short bf16x8;  // 8 bf16 (4 VGPRs)
typedef __attribute__((ext_vector_type(4))) float f32x4;

// tanh(v) = 1 - 2/(exp(2v)+1); exact at +-inf, ~1e-6 rel error (v_exp + v_rcp)
__device__ __forceinline__ float fast_tanh(float v) {
  const float e = __expf(2.0f * v);
  return 1.0f - 2.0f * __builtin_amdgcn_rcpf(e + 1.0f);
}

// f32 -> bf16 bits, round-to-nearest-even (inputs finite; no NaN path needed)
__device__ __forceinline__ short f2bf(float f) {
  const unsigned u = __float_as_uint(f);
  return (short)((u + 0x7FFFu + ((u >> 16) & 1u)) >> 16);
}

// pack two f32x4 (C/D-layout register quads) into one bf16x8 B-fragment
__device__ __forceinline__ bf16x8 pack2(const f32x4 s0, const f32x4 s1) {
  bf16x8 f;
  f[0] = f2bf(s0[0]); f[1] = f2bf(s0[1]); f[2] = f2bf(s0[2]); f[3] = f2bf(s0[3]);
  f[4] = f2bf(s1[0]); f[5] = f2bf(s1[1]); f[6] = f2bf(s1[2]); f[7] = f2bf(s1[3]);
  return f;
}

// ---------------------------------------------------------------------------
// Prep: pre-convert ALL weights into fragment-ordered bf16 in d_ws so both
// main kernels reload their full weight sets as coalesced dwordx4 (L2-hit).
// Round-4/5 lesson (rule #19): relying on regalloc to keep scattered-gathered
// fragments resident is luck — when it loses, the kernel re-materializes
// hundreds of scattered 4 B loads per iteration (capture 165 us round 4,
// recur 155 us round 5, VGPR_Count 84/120 = the tell).
// Fragment map (64 lanes x 16 B each):
//   [0,16)  capture w1t[m=f>>2][kk=f&3]          std k-map on Wc1
//   [16,24) capture w2t[(f-16)>>1][(f-16)&1]     custom k-map on Wc2
//   [24,32) recur   w1h[(f-24)>>1][(f-24)&1]     custom k-map on Wp1 (h rows)
//   [32,40) recur   w2t[(f-32)>>1][(f-32)&1]     custom k-map on Wp2
//   [40,44) recur   w1a[f-40]                    std a-map on Wp1 rows HID+
// ---------------------------------------------------------------------------
__global__ void prep_weights(const float* __restrict__ Wc1,
                             const float* __restrict__ Wc2,
                             const float* __restrict__ Wp1,
                             const float* __restrict__ Wp2,
                             short* __restrict__ ws)
{
  const int idx = blockIdx.x * blockDim.x + threadIdx.x;  // 0..(44*64-1)
  if (idx >= 44 * 64) return;
  const int f = idx >> 6, lane = idx & 63;
  const int r = lane & 15, G = lane >> 4;
  short o[8];
  if (f < 16) {
    const int m = f >> 2, kk = f & 3;  // std: k = 32kk + 8G + j
#pragma unroll
    for (int j = 0; j < 8; ++j)
      o[j] = f2bf(Wc1[(kk * 32 + 8 * G + j) * HID + 16 * m + r]);
  } else if (f < 40) {
    const int q = (f < 24) ? (f - 16) : (f < 32) ? (f - 24) : (f - 32);
    const float* W = (f < 24) ? Wc2 : (f < 32) ? Wp1 : Wp2;
    const int m = q >> 1, kk = q & 1;  // custom k-map (matches lane-resident C/D)
#pragma unroll
    for (int j = 0; j < 8; ++j) {
      const int k = (j < 4) ? (32 * kk + 4 * G + j)
                            : (32 * kk + 16 + 4 * G + (j - 4));
      o[j] = f2bf(W[k * HID + 16 * m + r]);
    }
  } else {
    const int m = f - 40;  // a-part, std map: k = HID + 8G + j
#pragma unroll
    for (int j = 0; j < 8; ++j)
      o[j] = f2bf(Wp1[(HID + 8 * G + j) * HID + 16 * m + r]);
  }
  bf16x8 v;
#pragma unroll
  for (int j = 0; j < 8; ++j) v[j] = o[j];
  *(bf16x8*)(ws + (size_t)idx * 8) = v;
}

// ---------------------------------------------------------------------------
// Phase 1: capture  z1 = tanh(tanh(x @ Wc1 + bc1) @ Wc2 + bc2), MFMA bf16.
// Transposed-operand formulation (validated rounds 3-5): C1^T = Wc1^T x^T;
// layer-2 consumes layer-1's lane-resident output directly as B-fragments.
// Weights from fragment-ordered ws (coalesced dwordx4), pinned in VGPRs.
// Round-5 result: ~70 us, near the ~64 us memory floor.
// ---------------------------------------------------------------------------
__global__ __launch_bounds__(256, 2) void capture_mfma(
    const float* __restrict__ x,
    const short* __restrict__ wsw,
    const float* __restrict__ bc1, const float* __restrict__ bc2,
    float* __restrict__ capt)
{
  const int tid  = threadIdx.x;
  const int lane = tid & 63;
  const int r    = lane & 15;   // tile-row (N dim)
  const int G    = lane >> 4;   // k-group
  const int wave = blockIdx.x * (blockDim.x >> 6) + (tid >> 6);
  const int nwaves = gridDim.x * (blockDim.x >> 6);

  const bf16x8* wf = (const bf16x8*)wsw;
  bf16x8 w1t[4][4];
#pragma unroll
  for (int m = 0; m < 4; ++m)
#pragma unroll
    for (int kk = 0; kk < 4; ++kk)
      w1t[m][kk] = wf[(m * 4 + kk) * 64 + lane];
  bf16x8 w2t[4][2];
#pragma unroll
  for (int m = 0; m < 4; ++m)
#pragma unroll
    for (int kk = 0; kk < 2; ++kk)
      w2t[m][kk] = wf[(16 + m * 2 + kk) * 64 + lane];
  f32x4 bias1[4], bias2[4];
#pragma unroll
  for (int m = 0; m < 4; ++m) {
    bias1[m] = *(const f32x4*)(bc1 + 16 * m + 4 * G);
    bias2[m] = *(const f32x4*)(bc2 + 16 * m + 4 * G);
  }
  // pin fragments in VGPRs so they stay resident across the tile loop
#pragma unroll
  for (int m = 0; m < 4; ++m) {
#pragma unroll
    for (int kk = 0; kk < 4; ++kk) asm volatile("" : "+v"(w1t[m][kk]));
#pragma unroll
    for (int kk = 0; kk < 2; ++kk) asm volatile("" : "+v"(w2t[m][kk]));
    asm volatile("" : "+v"(bias1[m]), "+v"(bias2[m]));
  }

  for (int tile = wave; tile < (TT * BB) / 16; tile += nwaves) {
    const float* xrow = x + ((size_t)tile * 16 + r) * OBS;
    bf16x8 xa[4];
#pragma unroll
    for (int kk = 0; kk < 4; ++kk) {
      const float4 lo = *(const float4*)(xrow + kk * 32 + 8 * G);
      const float4 hi = *(const float4*)(xrow + kk * 32 + 8 * G + 4);
      bf16x8 f;
      f[0] = f2bf(lo.x); f[1] = f2bf(lo.y); f[2] = f2bf(lo.z); f[3] = f2bf(lo.w);
      f[4] = f2bf(hi.x); f[5] = f2bf(hi.y); f[6] = f2bf(hi.z); f[7] = f2bf(hi.w);
      xa[kk] = f;
    }

    float um[4][4];
#pragma unroll
    for (int m = 0; m < 4; ++m) {
      f32x4 acc = bias1[m];
#pragma unroll
      for (int kk = 0; kk < 4; ++kk)
        acc = __builtin_amdgcn_mfma_f32_16x16x32_bf16(w1t[m][kk], xa[kk], acc, 0, 0, 0);
#pragma unroll
      for (int q = 0; q < 4; ++q) um[m][q] = fast_tanh(acc[q]);
    }

    bf16x8 b2[2];
#pragma unroll
    for (int kk = 0; kk < 2; ++kk) {
      bf16x8 f;
#pragma unroll
      for (int j = 0; j < 4; ++j) f[j]     = f2bf(um[2 * kk][j]);
#pragma unroll
      for (int j = 0; j < 4; ++j) f[4 + j] = f2bf(um[2 * kk + 1][j]);
      b2[kk] = f;
    }

    float* crow = capt + ((size_t)tile * 16 + r) * HID;
#pragma unroll
    for (int m = 0; m < 4; ++m) {
      f32x4 acc = bias2[m];
#pragma unroll
      for (int kk = 0; kk < 2; ++kk)
        acc = __builtin_amdgcn_mfma_f32_16x16x32_bf16(w2t[m][kk], b2[kk], acc, 0, 0, 0);
      float4 o;
      o.x = fast_tanh(acc[0]); o.y = fast_tanh(acc[1]);
      o.z = fast_tanh(acc[2]); o.w = fast_tanh(acc[3]);
      *(float4*)(crow + 16 * m + 4 * G) = o;
    }
  }
}

// ---------------------------------------------------------------------------
// Phase 2: recurrence, MFMA bf16, transposed-operand form. One wave owns 16
// batch rows for the whole T-scan; h stays in registers in the MFMA C/D
// layout; layer-2 output layout == next step's layer-1 B-fragment layout.
// NEW vs round 5: weights come from the prep kernel's fragment-ordered ws
// (20 coalesced dwordx4) and are pinned — removes the remat pathology
// (round 5: VGPR_Count=120, scattered weight gather re-issued every step,
// 155 us). Pinned state 112 regs + ~110 working < 256 budget -> no spill.
// ---------------------------------------------------------------------------
#define R_LOADS(t, Z, AL, AH, GV)                                   \
  do {                                                              \
    const size_t rb = (size_t)(t) * BB + row;                       \
    const float* zp = z1buf + rb * HID;                             \
    Z##0 = *(const f32x4*)(zp + 4 * G);                             \
    Z##1 = *(const f32x4*)(zp + 16 + 4 * G);                        \
    Z##2 = *(const f32x4*)(zp + 32 + 4 * G);                        \
    Z##3 = *(const f32x4*)(zp + 48 + 4 * G);                        \
    const float* ap = a + rb * ACT + 8 * G;                         \
    AL = *(const float4*)(ap);                                      \
    AH = *(const float4*)(ap + 4);                                  \
    GV = g[rb];                                                     \
  } while (0)

#define R_COMPUTE(t, Z0, Z1, Z2, Z3, AL, AH, GV)                               \
  do {                                                                         \
    bf16x8 ab;                                                                 \
    ab[0] = f2bf(AL.x); ab[1] = f2bf(AL.y); ab[2] = f2bf(AL.z);                \
    ab[3] = f2bf(AL.w); ab[4] = f2bf(AH.x); ab[5] = f2bf(AH.y);                \
    ab[6] = f2bf(AH.z); ab[7] = f2bf(AH.w);                                    \
    f32x4 um[4];                                                               \
    _Pragma("unroll")                                                          \
    for (int m = 0; m < 4; ++m) {                                              \
      f32x4 acc = bias1[m];                                                    \
      acc = __builtin_amdgcn_mfma_f32_16x16x32_bf16(w1h[m][0], hb0, acc, 0, 0, 0); \
      acc = __builtin_amdgcn_mfma_f32_16x16x32_bf16(w1h[m][1], hb1, acc, 0, 0, 0); \
      acc = __builtin_amdgcn_mfma_f32_16x16x32_bf16(w1a[m], ab, acc, 0, 0, 0); \
      f32x4 u;                                                                 \
      u[0] = fast_tanh(acc[0]); u[1] = fast_tanh(acc[1]);                      \
      u[2] = fast_tanh(acc[2]); u[3] = fast_tanh(acc[3]);                      \
      um[m] = u;                                                               \
    }                                                                          \
    const bf16x8 ub0 = pack2(um[0], um[1]);                                    \
    const bf16x8 ub1 = pack2(um[2], um[3]);                                    \
    const size_t ob = ((size_t)(t) * BB + row) * HID;                          \
    _Pragma("unroll")                                                          \
    for (int m = 0; m < 4; ++m) {                                              \
      f32x4 acc = bias2[m];                                                    \
      acc = __builtin_amdgcn_mfma_f32_16x16x32_bf16(w2t[m][0], ub0, acc, 0, 0, 0); \
      acc = __builtin_amdgcn_mfma_f32_16x16x32_bf16(w2t[m][1], ub1, acc, 0, 0, 0); \
      const f32x4 zz = (m == 0) ? Z0 : (m == 1) ? Z1 : (m == 2) ? Z2 : Z3;     \
      f32x4 hn;                                                                \
      hn[0] = fmaf(GV, fast_tanh(acc[0]) - zz[0], zz[0]);                      \
      hn[1] = fmaf(GV, fast_tanh(acc[1]) - zz[1], zz[1]);                      \
      hn[2] = fmaf(GV, fast_tanh(acc[2]) - zz[2], zz[2]);                      \
      hn[3] = fmaf(GV, fast_tanh(acc[3]) - zz[3], zz[3]);                      \
      hm[m] = hn;                                                              \
      *(f32x4*)(outs + ob + 16 * m + 4 * G) = hn;                              \
    }                                                                          \
    hb0 = pack2(hm[0], hm[1]);                                                 \
    hb1 = pack2(hm[2], hm[3]);                                                 \
  } while (0)

__global__ __launch_bounds__(64, 1) void recur_mfma(
    const float* __restrict__ h0,
    const float* __restrict__ g,
    const float* __restrict__ a,
    const short* __restrict__ wsw,
    const float* __restrict__ bp1, const float* __restrict__ bp2,
    const float* __restrict__ z1buf,
    float* __restrict__ outs, float* __restrict__ hlast)
{
  const int lane = threadIdx.x & 63;
  const int r    = lane & 15;
  const int G    = lane >> 4;
  const int row  = blockIdx.x * 16 + r;   // batch row owned by this lane

  // ---- weight fragments: coalesced loads from prep buffer, then pinned ----
  const bf16x8* wf = (const bf16x8*)wsw;
  bf16x8 w1h[4][2], w2t[4][2], w1a[4];
#pragma unroll
  for (int m = 0; m < 4; ++m) {
#pragma unroll
    for (int kk = 0; kk < 2; ++kk) {
      w1h[m][kk] = wf[(24 + m * 2 + kk) * 64 + lane];
      w2t[m][kk] = wf[(32 + m * 2 + kk) * 64 + lane];
    }
    w1a[m] = wf[(40 + m) * 64 + lane];
  }
  f32x4 bias1[4], bias2[4];
#pragma unroll
  for (int m = 0; m < 4; ++m) {
    bias1[m] = *(const f32x4*)(bp1 + 16 * m + 4 * G);
    bias2[m] = *(const f32x4*)(bp2 + 16 * m + 4 * G);
  }
#pragma unroll
  for (int m = 0; m < 4; ++m) {
#pragma unroll
    for (int kk = 0; kk < 2; ++kk)
      asm volatile("" : "+v"(w1h[m][kk]), "+v"(w2t[m][kk]));
    asm volatile("" : "+v"(w1a[m]));
    asm volatile("" : "+v"(bias1[m]), "+v"(bias2[m]));
  }

  // ---- h state in C/D layout ----
  f32x4 hm[4];
#pragma unroll
  for (int m = 0; m < 4; ++m)
    hm[m] = *(const f32x4*)(h0 + (size_t)row * HID + 16 * m + 4 * G);
  bf16x8 hb0 = pack2(hm[0], hm[1]);
  bf16x8 hb1 = pack2(hm[2], hm[3]);

  // ---- double-buffered step inputs ----
  f32x4 zA0, zA1, zA2, zA3, zB0, zB1, zB2, zB3;
  float4 aAl, aAh, aBl, aBh;
  float gA, gB;

  R_LOADS(0, zA, aAl, aAh, gA);

  for (int t = 0; t < TT; t += 2) {
    const int t2 = (t + 2 < TT) ? (t + 2) : (TT - 1);  // clamp (redundant reload)
    R_LOADS(t + 1, zB, aBl, aBh, gB);
    R_COMPUTE(t, zA0, zA1, zA2, zA3, aAl, aAh, gA);
    R_LOADS(t2, zA, aAl, aAh, gA);
    R_COMPUTE(t + 1, zB0, zB1, zB2, zB3, aBl, aBh, gB);
  }

#pragma unroll
  for (int m = 0; m < 4; ++m)
    *(f32x4*)(hlast + (size_t)row * HID + 16 * m + 4 * G) = hm[m];
}

extern "C" void kernel_launch(void* const* d_in, const int* in_sizes, int n_in,
                              void* d_out, int out_size, void* d_ws, size_t ws_size,
                              hipStream_t stream) {
  const float* x   = (const float*)d_in[0];
  const float* h0  = (const float*)d_in[1];
  const float* g   = (const float*)d_in[2];
  const float* a   = (const float*)d_in[3];
  const float* Wc1 = (const float*)d_in[4];
  const float* bc1 = (const float*)d_in[5];
  const float* Wc2 = (const float*)d_in[6];
  const float* bc2 = (const float*)d_in[7];
  const float* Wp1 = (const float*)d_in[8];
  const float* bp1 = (const float*)d_in[9];
  const float* Wp2 = (const float*)d_in[10];
  const float* bp2 = (const float*)d_in[11];

  float* out   = (float*)d_out;
  float* outs  = out;                                   // [T,B,H]
  float* hlast = out + (size_t)TT * BB * HID;           // [1,B,H]
  float* capt  = hlast + (size_t)BB * HID;              // [T,B,H]
  short* wsw   = (short*)d_ws;                          // 44 KB fragment buffer

  prep_weights<<<dim3(11), dim3(256), 0, stream>>>(Wc1, Wc2, Wp1, Wp2, wsw);
  capture_mfma<<<dim3(2048), dim3(256), 0, stream>>>(x, wsw, bc1, bc2, capt);
  recur_mfma<<<dim3(BB / 16), dim3(64), 0, stream>>>(h0, g, a, wsw, bp1, bp2,
                                                     capt, outs, hlast);
}

// Round 7
// 227.259 us; speedup vs baseline: 5.0172x; 1.0036x over previous
//
#include <hip/hip_runtime.h>

#define OBS 128
#define HID 64
#define ACT 32
#define TT  128
#define BB  4096

typedef __attribute__((ext_vector_type(8))) short bf16x8;  // 8 bf16 (4 VGPRs)
typedef __attribute__((ext_vector_type(4))) float f32x4;

// tanh(v) = 1 - 2/(exp(2v)+1); exact at +-inf, ~1e-6 rel error (v_exp + v_rcp)
__device__ __forceinline__ float fast_tanh(float v) {
  const float e = __expf(2.0f * v);
  return 1.0f - 2.0f * __builtin_amdgcn_rcpf(e + 1.0f);
}

// f32 -> bf16 bits, round-to-nearest-even (inputs finite; no NaN path needed)
__device__ __forceinline__ short f2bf(float f) {
  const unsigned u = __float_as_uint(f);
  return (short)((u + 0x7FFFu + ((u >> 16) & 1u)) >> 16);
}

// pack two f32 -> one u32 of 2 bf16 (lo, hi)
__device__ __forceinline__ unsigned int pk2(float x, float y) {
  return (unsigned int)(unsigned short)f2bf(x) |
         ((unsigned int)(unsigned short)f2bf(y) << 16);
}

// pack two f32x4 (C/D-layout register quads) into one bf16x8 B-fragment
__device__ __forceinline__ bf16x8 pack2(const f32x4 s0, const f32x4 s1) {
  bf16x8 f;
  f[0] = f2bf(s0[0]); f[1] = f2bf(s0[1]); f[2] = f2bf(s0[2]); f[3] = f2bf(s0[3]);
  f[4] = f2bf(s1[0]); f[5] = f2bf(s1[1]); f[6] = f2bf(s1[2]); f[7] = f2bf(s1[3]);
  return f;
}

// LDS-only barrier: wait own ds ops, sync waves. Deliberately NOT
// __syncthreads(), which drains vmcnt(0) and would serialize the global
// prefetch/stores every step (the barrier-drain trap).
__device__ __forceinline__ void lds_barrier() {
  asm volatile("s_waitcnt lgkmcnt(0)" ::: "memory");
  __builtin_amdgcn_s_barrier();
  asm volatile("" ::: "memory");
}

// read one B-fragment half-pair from an exchange row: two b64 at c0, c0+16
__device__ __forceinline__ bf16x8 rdfrag(const unsigned short* base, int rr, int c0) {
  const uint2 q0 = *(const uint2*)(base + rr * 72 + c0);
  const uint2 q1 = *(const uint2*)(base + rr * 72 + c0 + 16);
  union { bf16x8 f; unsigned int u[4]; } z;
  z.u[0] = q0.x; z.u[1] = q0.y; z.u[2] = q1.x; z.u[3] = q1.y;
  return z.f;
}

// ---------------------------------------------------------------------------
// Prep: pre-convert ALL weights into fragment-ordered bf16 in d_ws (verbatim
// from round 6). Fragment map (64 lanes x 16 B each):
//   [0,16)  capture w1t[m=f>>2][kk=f&3]          std k-map on Wc1
//   [16,24) capture w2t[(f-16)>>1][(f-16)&1]     custom k-map on Wc2
//   [24,32) recur   w1h[(f-24)>>1][(f-24)&1]     custom k-map on Wp1 (h rows)
//   [32,40) recur   w2t[(f-32)>>1][(f-32)&1]     custom k-map on Wp2
//   [40,44) recur   w1a[f-40]                    std a-map on Wp1 rows HID+
// ---------------------------------------------------------------------------
__global__ void prep_weights(const float* __restrict__ Wc1,
                             const float* __restrict__ Wc2,
                             const float* __restrict__ Wp1,
                             const float* __restrict__ Wp2,
                             short* __restrict__ ws)
{
  const int idx = blockIdx.x * blockDim.x + threadIdx.x;  // 0..(44*64-1)
  if (idx >= 44 * 64) return;
  const int f = idx >> 6, lane = idx & 63;
  const int r = lane & 15, G = lane >> 4;
  short o[8];
  if (f < 16) {
    const int m = f >> 2, kk = f & 3;  // std: k = 32kk + 8G + j
#pragma unroll
    for (int j = 0; j < 8; ++j)
      o[j] = f2bf(Wc1[(kk * 32 + 8 * G + j) * HID + 16 * m + r]);
  } else if (f < 40) {
    const int q = (f < 24) ? (f - 16) : (f < 32) ? (f - 24) : (f - 32);
    const float* W = (f < 24) ? Wc2 : (f < 32) ? Wp1 : Wp2;
    const int m = q >> 1, kk = q & 1;  // custom k-map (matches lane-resident C/D)
#pragma unroll
    for (int j = 0; j < 8; ++j) {
      const int k = (j < 4) ? (32 * kk + 4 * G + j)
                            : (32 * kk + 16 + 4 * G + (j - 4));
      o[j] = f2bf(W[k * HID + 16 * m + r]);
    }
  } else {
    const int m = f - 40;  // a-part, std map: k = HID + 8G + j
#pragma unroll
    for (int j = 0; j < 8; ++j)
      o[j] = f2bf(Wp1[(HID + 8 * G + j) * HID + 16 * m + r]);
  }
  bf16x8 v;
#pragma unroll
  for (int j = 0; j < 8; ++j) v[j] = o[j];
  *(bf16x8*)(ws + (size_t)idx * 8) = v;
}

// ---------------------------------------------------------------------------
// Phase 1: capture  z1 = tanh(tanh(x @ Wc1 + bc1) @ Wc2 + bc2), MFMA bf16
// (verbatim from rounds 5/6; ~70 us when codegen cooperates, floor ~64 us).
// ---------------------------------------------------------------------------
__global__ __launch_bounds__(256, 2) void capture_mfma(
    const float* __restrict__ x,
    const short* __restrict__ wsw,
    const float* __restrict__ bc1, const float* __restrict__ bc2,
    float* __restrict__ capt)
{
  const int tid  = threadIdx.x;
  const int lane = tid & 63;
  const int r    = lane & 15;   // tile-row (N dim)
  const int G    = lane >> 4;   // k-group
  const int wave = blockIdx.x * (blockDim.x >> 6) + (tid >> 6);
  const int nwaves = gridDim.x * (blockDim.x >> 6);

  const bf16x8* wf = (const bf16x8*)wsw;
  bf16x8 w1t[4][4];
#pragma unroll
  for (int m = 0; m < 4; ++m)
#pragma unroll
    for (int kk = 0; kk < 4; ++kk)
      w1t[m][kk] = wf[(m * 4 + kk) * 64 + lane];
  bf16x8 w2t[4][2];
#pragma unroll
  for (int m = 0; m < 4; ++m)
#pragma unroll
    for (int kk = 0; kk < 2; ++kk)
      w2t[m][kk] = wf[(16 + m * 2 + kk) * 64 + lane];
  f32x4 bias1[4], bias2[4];
#pragma unroll
  for (int m = 0; m < 4; ++m) {
    bias1[m] = *(const f32x4*)(bc1 + 16 * m + 4 * G);
    bias2[m] = *(const f32x4*)(bc2 + 16 * m + 4 * G);
  }
  // pin fragments in VGPRs so they stay resident across the tile loop
#pragma unroll
  for (int m = 0; m < 4; ++m) {
#pragma unroll
    for (int kk = 0; kk < 4; ++kk) asm volatile("" : "+v"(w1t[m][kk]));
#pragma unroll
    for (int kk = 0; kk < 2; ++kk) asm volatile("" : "+v"(w2t[m][kk]));
    asm volatile("" : "+v"(bias1[m]), "+v"(bias2[m]));
  }

  for (int tile = wave; tile < (TT * BB) / 16; tile += nwaves) {
    const float* xrow = x + ((size_t)tile * 16 + r) * OBS;
    bf16x8 xa[4];
#pragma unroll
    for (int kk = 0; kk < 4; ++kk) {
      const float4 lo = *(const float4*)(xrow + kk * 32 + 8 * G);
      const float4 hi = *(const float4*)(xrow + kk * 32 + 8 * G + 4);
      bf16x8 f;
      f[0] = f2bf(lo.x); f[1] = f2bf(lo.y); f[2] = f2bf(lo.z); f[3] = f2bf(lo.w);
      f[4] = f2bf(hi.x); f[5] = f2bf(hi.y); f[6] = f2bf(hi.z); f[7] = f2bf(hi.w);
      xa[kk] = f;
    }

    float um[4][4];
#pragma unroll
    for (int m = 0; m < 4; ++m) {
      f32x4 acc = bias1[m];
#pragma unroll
      for (int kk = 0; kk < 4; ++kk)
        acc = __builtin_amdgcn_mfma_f32_16x16x32_bf16(w1t[m][kk], xa[kk], acc, 0, 0, 0);
#pragma unroll
      for (int q = 0; q < 4; ++q) um[m][q] = fast_tanh(acc[q]);
    }

    bf16x8 b2[2];
#pragma unroll
    for (int kk = 0; kk < 2; ++kk) {
      bf16x8 f;
#pragma unroll
      for (int j = 0; j < 4; ++j) f[j]     = f2bf(um[2 * kk][j]);
#pragma unroll
      for (int j = 0; j < 4; ++j) f[4 + j] = f2bf(um[2 * kk + 1][j]);
      b2[kk] = f;
    }

    float* crow = capt + ((size_t)tile * 16 + r) * HID;
#pragma unroll
    for (int m = 0; m < 4; ++m) {
      f32x4 acc = bias2[m];
#pragma unroll
      for (int kk = 0; kk < 2; ++kk)
        acc = __builtin_amdgcn_mfma_f32_16x16x32_bf16(w2t[m][kk], b2[kk], acc, 0, 0, 0);
      float4 o;
      o.x = fast_tanh(acc[0]); o.y = fast_tanh(acc[1]);
      o.z = fast_tanh(acc[2]); o.w = fast_tanh(acc[3]);
      *(float4*)(crow + 16 * m + 4 * G) = o;
    }
  }
}

// ---------------------------------------------------------------------------
// Phase 2: recurrence, MFMA bf16, 4-WAVE m-SPLIT (new this round).
// One block (4 waves) owns one 16-row batch tile; wave w computes output
// columns [16w,16w+16) of both layers. Per-wave persistent state is only
// 5 weight fragments + 2 biases (~28 VGPRs) — nothing for regalloc to spill
// or remat (the r4-r6 lottery). h and u are exchanged between waves each
// step via a tiny bf16 LDS buffer: owner writes its quarter as one b64,
// readers pull their B-fragments as two b64 each (no conversion). Stride 72
// shorts makes all accesses <=2-way bank-aliased (free, m136).
// Barriers are lgkmcnt-only so the z1/a/g prefetch and outs stores stay in
// flight across steps. Numerics identical to the r4/r5 register path.
// Grid: 256 blocks x 256 threads (4 waves/CU on the 4 SIMDs).
// ---------------------------------------------------------------------------
#define STEP4(TCUR, TNXT, Zc, Acl, Ach, Gc, Zn, Anl, Anh, Gn)                   \
  do {                                                                          \
    /* publish own h quarter (bf16) */                                          \
    *(uint2*)&hU[r][cq] = make_uint2(pk2(hm[0], hm[1]), pk2(hm[2], hm[3]));     \
    lds_barrier();                                                              \
    { /* prefetch next step's gate inputs (slack ~1.5 steps) */                 \
      const size_t rbn = (size_t)(TNXT) * BB + row;                             \
      Zn  = *(const f32x4*)(z1buf + rbn * HID + cq);                            \
      Anl = *(const float4*)(a + rbn * ACT + 8 * G);                            \
      Anh = *(const float4*)(a + rbn * ACT + 8 * G + 4);                        \
      Gn  = g[rbn];                                                             \
    }                                                                           \
    const bf16x8 hb0 = rdfrag(&hU[0][0], r, 4 * G);                             \
    const bf16x8 hb1 = rdfrag(&hU[0][0], r, 4 * G + 32);                        \
    bf16x8 ab;                                                                  \
    ab[0] = f2bf(Acl.x); ab[1] = f2bf(Acl.y); ab[2] = f2bf(Acl.z);              \
    ab[3] = f2bf(Acl.w); ab[4] = f2bf(Ach.x); ab[5] = f2bf(Ach.y);              \
    ab[6] = f2bf(Ach.z); ab[7] = f2bf(Ach.w);                                   \
    f32x4 acc = bias1;                                                          \
    acc = __builtin_amdgcn_mfma_f32_16x16x32_bf16(w1h0, hb0, acc, 0, 0, 0);     \
    acc = __builtin_amdgcn_mfma_f32_16x16x32_bf16(w1h1, hb1, acc, 0, 0, 0);     \
    acc = __builtin_amdgcn_mfma_f32_16x16x32_bf16(w1a,  ab,  acc, 0, 0, 0);     \
    /* publish own u quarter (bf16) */                                          \
    *(uint2*)&uU[r][cq] = make_uint2(pk2(fast_tanh(acc[0]), fast_tanh(acc[1])), \
                                     pk2(fast_tanh(acc[2]), fast_tanh(acc[3])));\
    lds_barrier();                                                              \
    const bf16x8 ub0 = rdfrag(&uU[0][0], r, 4 * G);                             \
    const bf16x8 ub1 = rdfrag(&uU[0][0], r, 4 * G + 32);                        \
    f32x4 acc2 = bias2;                                                         \
    acc2 = __builtin_amdgcn_mfma_f32_16x16x32_bf16(w2t0, ub0, acc2, 0, 0, 0);   \
    acc2 = __builtin_amdgcn_mfma_f32_16x16x32_bf16(w2t1, ub1, acc2, 0, 0, 0);   \
    f32x4 hn;                                                                   \
    hn[0] = fmaf(Gc, fast_tanh(acc2[0]) - Zc[0], Zc[0]);                        \
    hn[1] = fmaf(Gc, fast_tanh(acc2[1]) - Zc[1], Zc[1]);                        \
    hn[2] = fmaf(Gc, fast_tanh(acc2[2]) - Zc[2], Zc[2]);                        \
    hn[3] = fmaf(Gc, fast_tanh(acc2[3]) - Zc[3], Zc[3]);                        \
    hm = hn;                                                                    \
    *(f32x4*)(outs + ((size_t)(TCUR) * BB + row) * HID + cq) = hn;              \
  } while (0)

__global__ __launch_bounds__(256, 1) void recur_mfma4(
    const float* __restrict__ h0,
    const float* __restrict__ g,
    const float* __restrict__ a,
    const short* __restrict__ wsw,
    const float* __restrict__ bp1, const float* __restrict__ bp2,
    const float* __restrict__ z1buf,
    float* __restrict__ outs, float* __restrict__ hlast)
{
  const int tid  = threadIdx.x;
  const int lane = tid & 63;
  const int r    = lane & 15;                              // batch row in tile
  const int G    = (lane >> 4) & 3;                        // k-group
  const int w    = __builtin_amdgcn_readfirstlane(tid >> 6);  // m-quarter owner
  const int row  = blockIdx.x * 16 + r;
  const int cq   = 16 * w + 4 * G;                         // own column base

  __shared__ unsigned short hU[16][72];  // h exchange, bf16, 2-way-free stride
  __shared__ unsigned short uU[16][72];  // u exchange

  // ---- per-wave weights: 5 coalesced fragment loads, pinned ----
  const bf16x8* wf = (const bf16x8*)wsw;
  bf16x8 w1h0 = wf[(24 + 2 * w + 0) * 64 + lane];
  bf16x8 w1h1 = wf[(24 + 2 * w + 1) * 64 + lane];
  bf16x8 w2t0 = wf[(32 + 2 * w + 0) * 64 + lane];
  bf16x8 w2t1 = wf[(32 + 2 * w + 1) * 64 + lane];
  bf16x8 w1a  = wf[(40 + w) * 64 + lane];
  f32x4 bias1 = *(const f32x4*)(bp1 + cq);
  f32x4 bias2 = *(const f32x4*)(bp2 + cq);
  asm volatile("" : "+v"(w1h0), "+v"(w1h1), "+v"(w2t0), "+v"(w2t1), "+v"(w1a));
  asm volatile("" : "+v"(bias1), "+v"(bias2));

  // ---- own h quarter (f32) ----
  f32x4 hm = *(const f32x4*)(h0 + (size_t)row * HID + cq);

  // ---- 1-deep prefetch of (z1, a, g) ----
  f32x4 zA, zB;
  float4 aAl, aAh, aBl, aBh;
  float gA, gB;
  {
    zA  = *(const f32x4*)(z1buf + (size_t)row * HID + cq);
    aAl = *(const float4*)(a + (size_t)row * ACT + 8 * G);
    aAh = *(const float4*)(a + (size_t)row * ACT + 8 * G + 4);
    gA  = g[row];
  }

  for (int t = 0; t < TT; t += 2) {
    const int t2 = (t + 2 < TT) ? (t + 2) : (TT - 1);  // clamp (redundant reload)
    STEP4(t,     t + 1, zA, aAl, aAh, gA, zB, aBl, aBh, gB);
    STEP4(t + 1, t2,    zB, aBl, aBh, gB, zA, aAl, aAh, gA);
  }

  *(f32x4*)(hlast + (size_t)row * HID + cq) = hm;
}

extern "C" void kernel_launch(void* const* d_in, const int* in_sizes, int n_in,
                              void* d_out, int out_size, void* d_ws, size_t ws_size,
                              hipStream_t stream) {
  const float* x   = (const float*)d_in[0];
  const float* h0  = (const float*)d_in[1];
  const float* g   = (const float*)d_in[2];
  const float* a   = (const float*)d_in[3];
  const float* Wc1 = (const float*)d_in[4];
  const float* bc1 = (const float*)d_in[5];
  const float* Wc2 = (const float*)d_in[6];
  const float* bc2 = (const float*)d_in[7];
  const float* Wp1 = (const float*)d_in[8];
  const float* bp1 = (const float*)d_in[9];
  const float* Wp2 = (const float*)d_in[10];
  const float* bp2 = (const float*)d_in[11];

  float* out   = (float*)d_out;
  float* outs  = out;                                   // [T,B,H]
  float* hlast = out + (size_t)TT * BB * HID;           // [1,B,H]
  float* capt  = hlast + (size_t)BB * HID;              // [T,B,H]
  short* wsw   = (short*)d_ws;                          // 44 KB fragment buffer

  prep_weights<<<dim3(11), dim3(256), 0, stream>>>(Wc1, Wc2, Wp1, Wp2, wsw);
  capture_mfma<<<dim3(2048), dim3(256), 0, stream>>>(x, wsw, bc1, bc2, capt);
  recur_mfma4<<<dim3(BB / 16), dim3(256), 0, stream>>>(h0, g, a, wsw, bp1, bp2,
                                                       capt, outs, hlast);
}

// Round 9
// 220.015 us; speedup vs baseline: 5.1824x; 1.0329x over previous
//
#include <hip/hip_runtime.h>

#define OBS 128
#define HID 64
#define ACT 32
#define TT  128
#define BB  4096

typedef __attribute__((ext_vector_type(8))) short bf16x8;  // 8 bf16 (4 VGPRs)
typedef __attribute__((ext_vector_type(4))) float f32x4;

// tanh(v) = 1 - 2/(exp(2v)+1); exact at +-inf, ~1e-6 rel error (v_exp + v_rcp)
__device__ __forceinline__ float fast_tanh(float v) {
  const float e = __expf(2.0f * v);
  return 1.0f - 2.0f * __builtin_amdgcn_rcpf(e + 1.0f);
}

// f32 -> bf16 bits, round-to-nearest-even (inputs finite; no NaN path needed)
__device__ __forceinline__ short f2bf(float f) {
  const unsigned u = __float_as_uint(f);
  return (short)((u + 0x7FFFu + ((u >> 16) & 1u)) >> 16);
}

// pack two f32 -> one u32 of 2 bf16 (lo, hi)
__device__ __forceinline__ unsigned int pk2(float x, float y) {
  return (unsigned int)(unsigned short)f2bf(x) |
         ((unsigned int)(unsigned short)f2bf(y) << 16);
}

// LDS-only barrier: wait own ds ops, sync waves. Deliberately NOT
// __syncthreads(), which drains vmcnt(0) and would serialize the global
// prefetch/stores every step (the barrier-drain trap).
__device__ __forceinline__ void lds_barrier() {
  asm volatile("s_waitcnt lgkmcnt(0)" ::: "memory");
  __builtin_amdgcn_s_barrier();
  asm volatile("" ::: "memory");
}

// read one B-fragment half-pair from an exchange row: two b64 at c0, c0+16
__device__ __forceinline__ bf16x8 rdfrag(const unsigned short* base, int rr, int c0) {
  const uint2 q0 = *(const uint2*)(base + rr * 72 + c0);
  const uint2 q1 = *(const uint2*)(base + rr * 72 + c0 + 16);
  union { bf16x8 f; unsigned int u[4]; } z;
  z.u[0] = q0.x; z.u[1] = q0.y; z.u[2] = q1.x; z.u[3] = q1.y;
  return z.f;
}

// ---------------------------------------------------------------------------
// Prep: pre-convert ALL weights into fragment-ordered bf16 in d_ws (verbatim
// from round 6). Fragment map (64 lanes x 16 B each):
//   [0,16)  capture w1t[m=f>>2][kk=f&3]          std k-map on Wc1
//   [16,24) capture w2t[(f-16)>>1][(f-16)&1]     custom k-map on Wc2
//   [24,32) recur   w1h[(f-24)>>1][(f-24)&1]     custom k-map on Wp1 (h rows)
//   [32,40) recur   w2t[(f-32)>>1][(f-32)&1]     custom k-map on Wp2
//   [40,44) recur   w1a[f-40]                    std a-map on Wp1 rows HID+
// ---------------------------------------------------------------------------
__global__ void prep_weights(const float* __restrict__ Wc1,
                             const float* __restrict__ Wc2,
                             const float* __restrict__ Wp1,
                             const float* __restrict__ Wp2,
                             short* __restrict__ ws)
{
  const int idx = blockIdx.x * blockDim.x + threadIdx.x;  // 0..(44*64-1)
  if (idx >= 44 * 64) return;
  const int f = idx >> 6, lane = idx & 63;
  const int r = lane & 15, G = lane >> 4;
  short o[8];
  if (f < 16) {
    const int m = f >> 2, kk = f & 3;  // std: k = 32kk + 8G + j
#pragma unroll
    for (int j = 0; j < 8; ++j)
      o[j] = f2bf(Wc1[(kk * 32 + 8 * G + j) * HID + 16 * m + r]);
  } else if (f < 40) {
    const int q = (f < 24) ? (f - 16) : (f < 32) ? (f - 24) : (f - 32);
    const float* W = (f < 24) ? Wc2 : (f < 32) ? Wp1 : Wp2;
    const int m = q >> 1, kk = q & 1;  // custom k-map (matches lane-resident C/D)
#pragma unroll
    for (int j = 0; j < 8; ++j) {
      const int k = (j < 4) ? (32 * kk + 4 * G + j)
                            : (32 * kk + 16 + 4 * G + (j - 4));
      o[j] = f2bf(W[k * HID + 16 * m + r]);
    }
  } else {
    const int m = f - 40;  // a-part, std map: k = HID + 8G + j
#pragma unroll
    for (int j = 0; j < 8; ++j)
      o[j] = f2bf(Wp1[(HID + 8 * G + j) * HID + 16 * m + r]);
  }
  bf16x8 v;
#pragma unroll
  for (int j = 0; j < 8; ++j) v[j] = o[j];
  *(bf16x8*)(ws + (size_t)idx * 8) = v;
}

// ---------------------------------------------------------------------------
// Phase 1: capture  z1 = tanh(tanh(x @ Wc1 + bc1) @ Wc2 + bc2), MFMA bf16.
// Weights live in LDS, not VGPRs. Rounds 3-7 showed bimodal codegen
// (80 vs 165 us on identical source) because keeping 24 bf16x8 fragments
// register-resident is a regalloc gamble (rule #19). Each block stages the
// 24.5 KB fragment table into LDS once; every tile iteration re-reads its
// A-operands via ds_read_b128, and a per-iteration memory fence forbids
// cross-iteration residency — codegen has exactly one (cheap) behavior.
// LDS cost: 24 reads x ~8 cyc = 192 cyc/tile vs the 1200 cyc/tile HBM
// budget — fully hidden. 16 B/lane stride = conflict-free.
// ---------------------------------------------------------------------------
__global__ __launch_bounds__(256, 2) void capture_lds(
    const float* __restrict__ x,
    const short* __restrict__ wsw,
    const float* __restrict__ bc1, const float* __restrict__ bc2,
    float* __restrict__ capt)
{
  __shared__ bf16x8 wl[24 * 64];  // 24.5 KB fragment table

  const int tid  = threadIdx.x;
  const int lane = tid & 63;
  const int r    = lane & 15;   // tile-row (N dim)
  const int G    = lane >> 4;   // k-group
  const int wave = blockIdx.x * 4 + (tid >> 6);
  const int nwaves = gridDim.x * 4;

  // stage fragment table (coalesced 16 B/thread x 6 iters)
  for (int s = tid; s < 24 * 64; s += 256)
    wl[s] = ((const bf16x8*)wsw)[s];
  __syncthreads();

  f32x4 bias1[4], bias2[4];
#pragma unroll
  for (int m = 0; m < 4; ++m) {
    bias1[m] = *(const f32x4*)(bc1 + 16 * m + 4 * G);
    bias2[m] = *(const f32x4*)(bc2 + 16 * m + 4 * G);
  }

  for (int tile = wave; tile < (TT * BB) / 16; tile += nwaves) {
    // structural fence: weight ds_reads cannot be hoisted/CSE'd across
    // iterations -> per-iter LDS reads, deterministic codegen
    asm volatile("" ::: "memory");

    const float* xrow = x + ((size_t)tile * 16 + r) * OBS;
    bf16x8 xa[4];
#pragma unroll
    for (int kk = 0; kk < 4; ++kk) {
      const float4 lo = *(const float4*)(xrow + kk * 32 + 8 * G);
      const float4 hi = *(const float4*)(xrow + kk * 32 + 8 * G + 4);
      bf16x8 f;
      f[0] = f2bf(lo.x); f[1] = f2bf(lo.y); f[2] = f2bf(lo.z); f[3] = f2bf(lo.w);
      f[4] = f2bf(hi.x); f[5] = f2bf(hi.y); f[6] = f2bf(hi.z); f[7] = f2bf(hi.w);
      xa[kk] = f;
    }

    float um[4][4];
#pragma unroll
    for (int m = 0; m < 4; ++m) {
      f32x4 acc = bias1[m];
#pragma unroll
      for (int kk = 0; kk < 4; ++kk)
        acc = __builtin_amdgcn_mfma_f32_16x16x32_bf16(wl[(m * 4 + kk) * 64 + lane],
                                                      xa[kk], acc, 0, 0, 0);
#pragma unroll
      for (int q = 0; q < 4; ++q) um[m][q] = fast_tanh(acc[q]);
    }

    bf16x8 b2[2];
#pragma unroll
    for (int kk = 0; kk < 2; ++kk) {
      bf16x8 f;
#pragma unroll
      for (int j = 0; j < 4; ++j) f[j]     = f2bf(um[2 * kk][j]);
#pragma unroll
      for (int j = 0; j < 4; ++j) f[4 + j] = f2bf(um[2 * kk + 1][j]);
      b2[kk] = f;
    }

    float* crow = capt + ((size_t)tile * 16 + r) * HID;
#pragma unroll
    for (int m = 0; m < 4; ++m) {
      f32x4 acc = bias2[m];
#pragma unroll
      for (int kk = 0; kk < 2; ++kk)
        acc = __builtin_amdgcn_mfma_f32_16x16x32_bf16(wl[(16 + m * 2 + kk) * 64 + lane],
                                                      b2[kk], acc, 0, 0, 0);
      float4 o;
      o.x = fast_tanh(acc[0]); o.y = fast_tanh(acc[1]);
      o.z = fast_tanh(acc[2]); o.w = fast_tanh(acc[3]);
      *(float4*)(crow + 16 * m + 4 * G) = o;
    }
  }
}

// ---------------------------------------------------------------------------
// Phase 2: recurrence, MFMA bf16, 4-wave m-split — BYTE-IDENTICAL to round 7
// (single controlled variable this round). One block (4 waves) owns one
// 16-row batch tile; wave w computes output columns [16w,16w+16); h/u are
// exchanged via a tiny bf16 LDS buffer with lgkmcnt-only barriers; per-wave
// persistent state is only ~28 VGPRs so regalloc has nothing to ruin.
// ---------------------------------------------------------------------------
#define STEP4(TCUR, TNXT, Zc, Acl, Ach, Gc, Zn, Anl, Anh, Gn)                   \
  do {                                                                          \
    /* publish own h quarter (bf16) */                                          \
    *(uint2*)&hU[r][cq] = make_uint2(pk2(hm[0], hm[1]), pk2(hm[2], hm[3]));     \
    lds_barrier();                                                              \
    { /* prefetch next step's gate inputs (slack ~1.5 steps) */                 \
      const size_t rbn = (size_t)(TNXT) * BB + row;                             \
      Zn  = *(const f32x4*)(z1buf + rbn * HID + cq);                            \
      Anl = *(const float4*)(a + rbn * ACT + 8 * G);                            \
      Anh = *(const float4*)(a + rbn * ACT + 8 * G + 4);                        \
      Gn  = g[rbn];                                                             \
    }                                                                           \
    const bf16x8 hb0 = rdfrag(&hU[0][0], r, 4 * G);                             \
    const bf16x8 hb1 = rdfrag(&hU[0][0], r, 4 * G + 32);                        \
    bf16x8 ab;                                                                  \
    ab[0] = f2bf(Acl.x); ab[1] = f2bf(Acl.y); ab[2] = f2bf(Acl.z);              \
    ab[3] = f2bf(Acl.w); ab[4] = f2bf(Ach.x); ab[5] = f2bf(Ach.y);              \
    ab[6] = f2bf(Ach.z); ab[7] = f2bf(Ach.w);                                   \
    f32x4 acc = bias1;                                                          \
    acc = __builtin_amdgcn_mfma_f32_16x16x32_bf16(w1h0, hb0, acc, 0, 0, 0);     \
    acc = __builtin_amdgcn_mfma_f32_16x16x32_bf16(w1h1, hb1, acc, 0, 0, 0);     \
    acc = __builtin_amdgcn_mfma_f32_16x16x32_bf16(w1a,  ab,  acc, 0, 0, 0);     \
    /* publish own u quarter (bf16) */                                          \
    *(uint2*)&uU[r][cq] = make_uint2(pk2(fast_tanh(acc[0]), fast_tanh(acc[1])), \
                                     pk2(fast_tanh(acc[2]), fast_tanh(acc[3])));\
    lds_barrier();                                                              \
    const bf16x8 ub0 = rdfrag(&uU[0][0], r, 4 * G);                             \
    const bf16x8 ub1 = rdfrag(&uU[0][0], r, 4 * G + 32);                        \
    f32x4 acc2 = bias2;                                                         \
    acc2 = __builtin_amdgcn_mfma_f32_16x16x32_bf16(w2t0, ub0, acc2, 0, 0, 0);   \
    acc2 = __builtin_amdgcn_mfma_f32_16x16x32_bf16(w2t1, ub1, acc2, 0, 0, 0);   \
    f32x4 hn;                                                                   \
    hn[0] = fmaf(Gc, fast_tanh(acc2[0]) - Zc[0], Zc[0]);                        \
    hn[1] = fmaf(Gc, fast_tanh(acc2[1]) - Zc[1], Zc[1]);                        \
    hn[2] = fmaf(Gc, fast_tanh(acc2[2]) - Zc[2], Zc[2]);                        \
    hn[3] = fmaf(Gc, fast_tanh(acc2[3]) - Zc[3], Zc[3]);                        \
    hm = hn;                                                                    \
    *(f32x4*)(outs + ((size_t)(TCUR) * BB + row) * HID + cq) = hn;              \
  } while (0)

__global__ __launch_bounds__(256, 1) void recur_mfma4(
    const float* __restrict__ h0,
    const float* __restrict__ g,
    const float* __restrict__ a,
    const short* __restrict__ wsw,
    const float* __restrict__ bp1, const float* __restrict__ bp2,
    const float* __restrict__ z1buf,
    float* __restrict__ outs, float* __restrict__ hlast)
{
  const int tid  = threadIdx.x;
  const int lane = tid & 63;
  const int r    = lane & 15;                              // batch row in tile
  const int G    = (lane >> 4) & 3;                        // k-group
  const int w    = __builtin_amdgcn_readfirstlane(tid >> 6);  // m-quarter owner
  const int row  = blockIdx.x * 16 + r;
  const int cq   = 16 * w + 4 * G;                         // own column base

  __shared__ unsigned short hU[16][72];  // h exchange, bf16, 2-way-free stride
  __shared__ unsigned short uU[16][72];  // u exchange

  // ---- per-wave weights: 5 coalesced fragment loads, pinned ----
  const bf16x8* wf = (const bf16x8*)wsw;
  bf16x8 w1h0 = wf[(24 + 2 * w + 0) * 64 + lane];
  bf16x8 w1h1 = wf[(24 + 2 * w + 1) * 64 + lane];
  bf16x8 w2t0 = wf[(32 + 2 * w + 0) * 64 + lane];
  bf16x8 w2t1 = wf[(32 + 2 * w + 1) * 64 + lane];
  bf16x8 w1a  = wf[(40 + w) * 64 + lane];
  f32x4 bias1 = *(const f32x4*)(bp1 + cq);
  f32x4 bias2 = *(const f32x4*)(bp2 + cq);
  asm volatile("" : "+v"(w1h0), "+v"(w1h1), "+v"(w2t0), "+v"(w2t1), "+v"(w1a));
  asm volatile("" : "+v"(bias1), "+v"(bias2));

  // ---- own h quarter (f32) ----
  f32x4 hm = *(const f32x4*)(h0 + (size_t)row * HID + cq);

  // ---- 1-deep prefetch of (z1, a, g) ----
  f32x4 zA, zB;
  float4 aAl, aAh, aBl, aBh;
  float gA, gB;
  {
    zA  = *(const f32x4*)(z1buf + (size_t)row * HID + cq);
    aAl = *(const float4*)(a + (size_t)row * ACT + 8 * G);
    aAh = *(const float4*)(a + (size_t)row * ACT + 8 * G + 4);
    gA  = g[row];
  }

  for (int t = 0; t < TT; t += 2) {
    const int t2 = (t + 2 < TT) ? (t + 2) : (TT - 1);  // clamp (redundant reload)
    STEP4(t,     t + 1, zA, aAl, aAh, gA, zB, aBl, aBh, gB);
    STEP4(t + 1, t2,    zB, aBl, aBh, gB, zA, aAl, aAh, gA);
  }

  *(f32x4*)(hlast + (size_t)row * HID + cq) = hm;
}

extern "C" void kernel_launch(void* const* d_in, const int* in_sizes, int n_in,
                              void* d_out, int out_size, void* d_ws, size_t ws_size,
                              hipStream_t stream) {
  const float* x   = (const float*)d_in[0];
  const float* h0  = (const float*)d_in[1];
  const float* g   = (const float*)d_in[2];
  const float* a   = (const float*)d_in[3];
  const float* Wc1 = (const float*)d_in[4];
  const float* bc1 = (const float*)d_in[5];
  const float* Wc2 = (const float*)d_in[6];
  const float* bc2 = (const float*)d_in[7];
  const float* Wp1 = (const float*)d_in[8];
  const float* bp1 = (const float*)d_in[9];
  const float* Wp2 = (const float*)d_in[10];
  const float* bp2 = (const float*)d_in[11];

  float* out   = (float*)d_out;
  float* outs  = out;                                   // [T,B,H]
  float* hlast = out + (size_t)TT * BB * HID;           // [1,B,H]
  float* capt  = hlast + (size_t)BB * HID;              // [T,B,H]
  short* wsw   = (short*)d_ws;                          // 44 KB fragment buffer

  prep_weights<<<dim3(11), dim3(256), 0, stream>>>(Wc1, Wc2, Wp1, Wp2, wsw);
  capture_lds<<<dim3(2048), dim3(256), 0, stream>>>(x, wsw, bc1, bc2, capt);
  recur_mfma4<<<dim3(BB / 16), dim3(256), 0, stream>>>(h0, g, a, wsw, bp1, bp2,
                                                       capt, outs, hlast);
}